// Round 5
// baseline (537.612 us; speedup 1.0000x reference)
//
#include <hip/hip_runtime.h>
#include <stdint.h>
#include <stddef.h>

// JAX >= 0.5 defaults jax_threefry_partitionable=True (verified R1: absmax 0.0).
#define JAX_PARTITIONABLE 1

static constexpr int B_   = 32;
static constexpr int NGT_ = 20;
static constexpr int H_   = 64;
static constexpr int W_   = 100;
static constexpr int A_   = 9;
static constexpr int HW_  = H_ * W_;        // 6400
static constexpr int T_   = HW_ * A_;       // 57600
static constexpr int NB2_ = 75;             // blocks per image (192 thr x 4 cells)
static constexpr int SEG_ = 768;            // candidate segment per block
static constexpr uint32_t NUMFG_ = 128u;
static constexpr uint32_t RPNBATCH_ = 256u;
static constexpr int OUT0_ = B_ * T_;
static constexpr int OUTC_ = B_ * 4 * A_ * HW_;

// ---------------- Threefry-2x32-20 (bit-exact vs JAX) ----------------
struct TF2 { uint32_t a, b; };

__host__ __device__ constexpr uint32_t rotl32(uint32_t v, int r) {
  return (v << r) | (v >> (32 - r));
}

__host__ __device__ constexpr TF2 tf2x32(uint32_t k0, uint32_t k1,
                                         uint32_t x0, uint32_t x1) {
  uint32_t ks2 = k0 ^ k1 ^ 0x1BD11BDAu;
  x0 += k0; x1 += k1;
#define TFR_(r) x0 += x1; x1 = rotl32(x1, (r)); x1 ^= x0;
  TFR_(13) TFR_(15) TFR_(26) TFR_(6)
  x0 += k1;  x1 += ks2 + 1u;
  TFR_(17) TFR_(29) TFR_(16) TFR_(24)
  x0 += ks2; x1 += k0 + 2u;
  TFR_(13) TFR_(15) TFR_(26) TFR_(6)
  x0 += k0;  x1 += k1 + 3u;
  TFR_(17) TFR_(29) TFR_(16) TFR_(24)
  x0 += k1;  x1 += ks2 + 4u;
  TFR_(13) TFR_(15) TFR_(26) TFR_(6)
  x0 += ks2; x1 += k0 + 5u;
#undef TFR_
  return TF2{x0, x1};
}

#if JAX_PARTITIONABLE
static constexpr TF2 KFk = tf2x32(0u, 42u, 0u, 0u);
static constexpr TF2 KBk = tf2x32(0u, 42u, 0u, 1u);
static constexpr uint32_t KF0 = KFk.a, KF1 = KFk.b;
static constexpr uint32_t KB0 = KBk.a, KB1 = KBk.b;
#else
static constexpr TF2 R02 = tf2x32(0u, 42u, 0u, 2u);
static constexpr TF2 R13 = tf2x32(0u, 42u, 1u, 3u);
static constexpr uint32_t KF0 = R02.a, KF1 = R13.a;
static constexpr uint32_t KB0 = R02.b, KB1 = R13.b;
#endif

__device__ inline uint32_t mant23(uint32_t k0, uint32_t k1, uint32_t j) {
#if JAX_PARTITIONABLE
  TF2 r = tf2x32(k0, k1, 0u, j);
  return (r.a ^ r.b) >> 9;
#else
  constexpr uint32_t HALF_ = (uint32_t)((uint64_t)B_ * T_ / 2);
  uint32_t lo = (j < HALF_) ? j : j - HALF_;
  TF2 r = tf2x32(k0, k1, lo, lo + HALF_);
  return ((j < HALF_) ? r.a : r.b) >> 9;
#endif
}

// monotone float->uint key; fkey(+0) = 0x80000000; strictly monotone, equality-preserving
__device__ inline uint32_t fkey(float f) {
  uint32_t u = __float_as_uint(f);
  return (u & 0x80000000u) ? ~u : (u | 0x80000000u);
}

__constant__ float c_anc[9][4] = {
  { -84.f,  -40.f,  99.f,  55.f},
  {-176.f,  -88.f, 191.f, 103.f},
  {-360.f, -184.f, 375.f, 199.f},
  { -56.f,  -56.f,  71.f,  71.f},
  {-120.f, -120.f, 135.f, 135.f},
  {-248.f, -248.f, 263.f, 263.f},
  { -36.f,  -80.f,  51.f,  95.f},
  { -80.f, -168.f,  95.f, 183.f},
  {-168.f, -344.f, 183.f, 359.f},
};

// ---------------- K1: the ONE full IOU pass --------------------------------
// 4 consecutive cells/thread. Outputs per-anchor bestkey + argmax byte, and
// per-(b,g) block-partial maxima (plain stores; k2 reduces). Zeroes dcnt.
__global__ __launch_bounds__(192) void k1_iou(const float* __restrict__ gt,
                                              const float* __restrict__ im,
                                              uint32_t* __restrict__ gpart,
                                              uint32_t* __restrict__ bkey,
                                              uint32_t* __restrict__ barg,
                                              uint32_t* __restrict__ dcnt) {
#pragma clang fp contract(off)
  const int b = blockIdx.y;
  const int bx = blockIdx.x;
  const int tid = threadIdx.x;
  const int iq = bx * 192 + tid;             // [0, 14400)
  __shared__ float4 sbox[NGT_];
  __shared__ float sgar[NGT_];
  __shared__ uint32_t skey[NGT_];
  __shared__ uint32_t smask;

  if (bx == 0 && tid == 0) dcnt[b] = 0u;     // ticket counter for k2 (next dispatch)

  bool valid = false;
  if (tid < NGT_) {
    const float x1 = gt[(b * NGT_ + tid) * 5 + 0];
    const float y1 = gt[(b * NGT_ + tid) * 5 + 1];
    const float x2 = gt[(b * NGT_ + tid) * 5 + 2];
    const float y2 = gt[(b * NGT_ + tid) * 5 + 3];
    const float gw = x2 - x1 + 1.0f, gh = y2 - y1 + 1.0f;
    valid = !(gw == 1.0f && gh == 1.0f);
    sbox[tid] = make_float4(x1, y1, x2, y2);
    sgar[tid] = gw * gh;
    skey[tid] = 0u;
  }
  unsigned long long mv = __ballot(valid);   // wave 0 holds lanes 0..19
  if (tid == 0) smask = (uint32_t)mv;
  __syncthreads();

  const int aa = iq / 1600;                  // wave-uniform (1600 % 64 == 0)
  const int cell0 = (iq % 1600) * 4;
  const float imh = im[0], imw = im[1];
  const float bx1 = c_anc[aa][0], by1 = c_anc[aa][1];
  const float bx2 = c_anc[aa][2], by2 = c_anc[aa][3];

  float ax1[4], ay1[4], ax2[4], ay2[4], aarea[4];
  bool ins[4];
#pragma unroll
  for (int c = 0; c < 4; ++c) {
    const int cell = cell0 + c;
    const int wx = cell % W_, hy = cell / W_;
    ax1[c] = bx1 + wx * 16.0f;
    ay1[c] = by1 + hy * 16.0f;
    ax2[c] = bx2 + wx * 16.0f;
    ay2[c] = by2 + hy * 16.0f;
    ins[c] = (ax1[c] >= 0.0f) && (ay1[c] >= 0.0f) && (ax2[c] < imw) && (ay2[c] < imh);
    aarea[c] = (ax2[c] - ax1[c] + 1.0f) * (ay2[c] - ay1[c] + 1.0f);
  }

  uint32_t bk[4] = {0u, 0u, 0u, 0u};
  uint32_t ba[4] = {0u, 0u, 0u, 0u};
  const uint32_t mask = smask;
  const bool anyin = __ballot(ins[0] || ins[1] || ins[2] || ins[3]) != 0ull;

  if (anyin) {
    for (int g = 0; g < NGT_; ++g) {
      if (!((mask >> g) & 1u)) continue;
      const float4 gb = sbox[g];             // one ds_read_b128, broadcast
      const float gar = sgar[g];
      uint32_t gm = 0u;
#pragma unroll
      for (int c = 0; c < 4; ++c) {
        float iw = fminf(ax2[c], gb.z) - fmaxf(ax1[c], gb.x) + 1.0f;
        float ih = fminf(ay2[c], gb.w) - fmaxf(ay1[c], gb.y) + 1.0f;
        float inter = fmaxf(iw, 0.0f) * fmaxf(ih, 0.0f);
        float ua = aarea[c] + gar - inter;
        float ov = inter / ua;               // IEEE div, bit-exact vs numpy
        uint32_t k = ins[c] ? fkey(ov) : 0u;
        if (k > bk[c]) { bk[c] = k; ba[c] = (uint32_t)g; }  // first-max
        gm = k > gm ? k : gm;
      }
      for (int d = 1; d < 64; d <<= 1) {
        uint32_t o = (uint32_t)__shfl_xor((int)gm, d, 64);
        gm = (o > gm) ? o : gm;
      }
      if ((tid & 63) == 0) atomicMax(&skey[g], gm);
    }
  }
  __syncthreads();
  if (tid < NGT_) gpart[(b * NGT_ + tid) * NB2_ + bx] = skey[tid];  // plain store

  const size_t base = (size_t)b * T_ + (size_t)aa * HW_ + cell0;    // 16B aligned
  *(uint4*)(bkey + base) = make_uint4(bk[0], bk[1], bk[2], bk[3]);
  barg[base >> 2] = ba[0] | (ba[1] << 8) | (ba[2] << 16) | (ba[3] << 24);
}

// ---------------- find_kth over LDS histogram, 128 active threads ----------
__device__ inline void find_kth128(uint32_t* hist, int n, uint32_t target, int tid,
                                   uint32_t* wsum, uint32_t* res) {
  const int C = n >> 7;  // n / 128
  uint32_t s = 0, v = 0;
  int base = 0;
  if (tid < 128) {       // wave-uniform for 192-thread blocks
    base = tid * C;
    for (int i = 0; i < C; ++i) s += hist[base + i];
    v = s;
    for (int d = 1; d < 64; d <<= 1) {
      uint32_t u = (uint32_t)__shfl_up((int)v, d, 64);
      if ((tid & 63) >= d) v += u;
    }
    if ((tid & 63) == 63) wsum[tid >> 6] = v;
  }
  __syncthreads();
  if (tid < 128) {
    uint32_t woff = (tid >= 64) ? wsum[0] : 0u;
    uint32_t c = woff + v - s;
    for (int i = 0; i < C; ++i) {
      uint32_t h = hist[base + i];
      if (h != 0u && target >= c && target < c + h) {
        res[0] = (uint32_t)(base + i);
        res[1] = c;
      }
      c += h;
    }
  }
  __syncthreads();
}

// ---------------- K2: labels + compaction + (last block per b) selection ---
__global__ __launch_bounds__(192) void k2_label(const float* __restrict__ gt,
                                                const float* __restrict__ im,
                                                const uint32_t* __restrict__ gpart,
                                                const uint32_t* __restrict__ bkey,
                                                int8_t* __restrict__ labels,
                                                uint32_t* __restrict__ cntblk,
                                                uint32_t* __restrict__ cand,
                                                uint32_t* __restrict__ dcnt,
                                                uint32_t* __restrict__ cnt,
                                                uint32_t* __restrict__ sel) {
#pragma clang fp contract(off)
  const int b = blockIdx.y;
  const int bx = blockIdx.x;
  const int tid = threadIdx.x;
  const int iq = bx * 192 + tid;
  __shared__ float4 sbox[NGT_];
  __shared__ float sgar[NGT_];
  __shared__ uint32_t skey[NGT_];
  __shared__ uint32_t smask, sminG, sflag;
  __shared__ uint32_t swc[3];
  __shared__ uint32_t scnt2[2][NB2_];
  __shared__ uint32_t hist[4096];
  __shared__ uint32_t wsum[2];
  __shared__ uint32_t res[2];
  __shared__ uint32_t lcnt, stot[2];

  bool valid = false;
  if (tid < NGT_) {
    const float x1 = gt[(b * NGT_ + tid) * 5 + 0];
    const float y1 = gt[(b * NGT_ + tid) * 5 + 1];
    const float x2 = gt[(b * NGT_ + tid) * 5 + 2];
    const float y2 = gt[(b * NGT_ + tid) * 5 + 3];
    const float gw = x2 - x1 + 1.0f, gh = y2 - y1 + 1.0f;
    valid = !(gw == 1.0f && gh == 1.0f);
    sbox[tid] = make_float4(x1, y1, x2, y2);
    sgar[tid] = gw * gh;
    skey[tid] = 0u;
  }
  unsigned long long mv = __ballot(valid);
  if (tid == 0) smask = (uint32_t)mv;
  __syncthreads();
  // reduce gmax from k1's 75 per-block partials
  for (int idx = tid; idx < NGT_ * NB2_; idx += 192)
    atomicMax(&skey[idx / NB2_], gpart[b * NGT_ * NB2_ + idx]);
  __syncthreads();
  if (tid < 64) {
    uint32_t kk = 0xFFFFFFFFu;
    if (tid < NGT_ && ((smask >> tid) & 1u)) {
      uint32_t g = skey[tid];
      if (g > 0x80000000u) kk = g;   // exclude fkey(0) sentinel
    }
    for (int d = 1; d < 64; d <<= 1) {
      uint32_t o = (uint32_t)__shfl_xor((int)kk, d, 64);
      kk = (o < kk) ? o : kk;
    }
    if (tid == 0) sminG = kk;
  }
  __syncthreads();

  const int aa = iq / 1600;
  const int cell0 = (iq % 1600) * 4;
  const float imh = im[0], imw = im[1];
  const float bx1 = c_anc[aa][0], by1 = c_anc[aa][1];
  const float bx2 = c_anc[aa][2], by2 = c_anc[aa][3];
  const size_t base = (size_t)b * T_ + (size_t)aa * HW_ + cell0;
  const uint4 bk4 = *(const uint4*)(bkey + base);

  float ax1[4], ay1[4], ax2[4], ay2[4], aarea[4];
  bool ins[4], need[4];
  uint32_t bkv[4] = {bk4.x, bk4.y, bk4.z, bk4.w};
  int lab[4];
#pragma unroll
  for (int c = 0; c < 4; ++c) {
    const int cell = cell0 + c;
    const int wx = cell % W_, hy = cell / W_;
    ax1[c] = bx1 + wx * 16.0f;
    ay1[c] = by1 + hy * 16.0f;
    ax2[c] = bx2 + wx * 16.0f;
    ay2[c] = by2 + hy * 16.0f;
    ins[c] = (ax1[c] >= 0.0f) && (ay1[c] >= 0.0f) && (ax2[c] < imw) && (ay2[c] < imh);
    aarea[c] = (ax2[c] - ax1[c] + 1.0f) * (ay2[c] - ay1[c] + 1.0f);
    const float mo = __uint_as_float(bkv[c] & 0x7FFFFFFFu);
    lab[c] = -1;
    if (ins[c] && mo < 0.3f) lab[c] = 0;
    need[c] = ins[c] && bkv[c] >= sminG && mo < 0.7f;  // haskeep only possible here
    if (ins[c] && mo >= 0.7f) lab[c] = 1;
  }
  if (__ballot(need[0] || need[1] || need[2] || need[3]) != 0ull) {
    const uint32_t mask = smask;
    for (int g = 0; g < NGT_; ++g) {
      if (!((mask >> g) & 1u)) continue;
      const uint32_t gk = skey[g];
      if (gk <= 0x80000000u) continue;       // gt_max==0 -> 1e-5, never matches
      const float4 gb = sbox[g];
      const float gar = sgar[g];
#pragma unroll
      for (int c = 0; c < 4; ++c) {
        if (!need[c]) continue;
        float iw = fminf(ax2[c], gb.z) - fmaxf(ax1[c], gb.x) + 1.0f;
        float ih = fminf(ay2[c], gb.w) - fmaxf(ay1[c], gb.y) + 1.0f;
        float inter = fmaxf(iw, 0.0f) * fmaxf(ih, 0.0f);
        float ua = aarea[c] + gar - inter;
        float ov = inter / ua;
        if (fkey(ov) == gk) lab[c] = 1;
      }
    }
  }

  uint32_t lpack = 0, mant[4];
  int nf = 0, nb = 0;
#pragma unroll
  for (int c = 0; c < 4; ++c) {
    lpack |= ((uint32_t)(uint8_t)(int8_t)lab[c]) << (8 * c);
    mant[c] = 0u;
    if (lab[c] >= 0) {
      const int t = (cell0 + c) * A_ + aa;   // original anchor index (threefry j)
      mant[c] = mant23(lab[c] ? KF0 : KB0, lab[c] ? KF1 : KB1, (uint32_t)(b * T_ + t));
      if (lab[c] == 1) ++nf; else ++nb;
    }
  }
  *(uint32_t*)(labels + base) = lpack;

  // block-local compaction via packed wave prefix (nf|nb<<16), zero global atomics
  const int lane = tid & 63, wv = tid >> 6;
  uint32_t cpk = (uint32_t)nf | ((uint32_t)nb << 16);
  uint32_t incl = cpk;
  for (int d = 1; d < 64; d <<= 1) {
    uint32_t u = (uint32_t)__shfl_up((int)incl, d, 64);
    if (lane >= d) incl += u;
  }
  uint32_t wtot = (uint32_t)__shfl((int)incl, 63, 64);
  if (lane == 0) swc[wv] = wtot;
  __syncthreads();
  uint32_t woffF = 0, woffB = 0, totF = 0, totB = 0;
  for (int w = 0; w < 3; ++w) {
    uint32_t v = swc[w];
    if (w < wv) { woffF += v & 0xFFFFu; woffB += v >> 16; }
    totF += v & 0xFFFFu; totB += v >> 16;
  }
  uint32_t excl = incl - cpk;
  uint32_t posF = woffF + (excl & 0xFFFFu);
  uint32_t posB = woffB + (excl >> 16);
  uint32_t* dstF = cand + ((size_t)0 * B_ + b) * T_ + (size_t)bx * SEG_;
  uint32_t* dstB = cand + ((size_t)1 * B_ + b) * T_ + (size_t)bx * SEG_;
#pragma unroll
  for (int c = 0; c < 4; ++c) {
    if (lab[c] == 1) dstF[posF++] = mant[c];
    else if (lab[c] == 0) dstB[posB++] = mant[c];
  }
  if (tid == 0) {
    cntblk[(0 * B_ + b) * NB2_ + bx] = totF;
    cntblk[(1 * B_ + b) * NB2_ + bx] = totB;
  }

  // ---- ticket: last block of image b runs the selection ----
  __threadfence();
  __syncthreads();
  if (tid == 0) sflag = (atomicAdd(&dcnt[b], 1u) == (uint32_t)(NB2_ - 1)) ? 1u : 0u;
  __syncthreads();
  if (!sflag) return;
  __threadfence();

  if (tid == 0) { stot[0] = 0u; stot[1] = 0u; }
  __syncthreads();
  for (int idx = tid; idx < 2 * NB2_; idx += 192) {
    const int cls = idx / NB2_, sx = idx % NB2_;
    const uint32_t v = cntblk[(cls * B_ + b) * NB2_ + sx];
    scnt2[cls][sx] = v;
    atomicAdd(&stot[cls], v);
  }
  __syncthreads();
  const uint32_t cf = stot[0], cbn = stot[1];
  if (tid == 0) { cnt[b * 2 + 0] = cf; cnt[b * 2 + 1] = cbn; }

  for (int cls = 0; cls < 2; ++cls) {
    const uint32_t fgk = cf < NUMFG_ ? cf : NUMFG_;
    const uint32_t K = (cls == 0) ? NUMFG_ : RPNBATCH_ - fgk;
    const uint32_t n = (cls == 0) ? cf : cbn;
    if (n <= K) {  // block-uniform branch
      if (tid == 0) { sel[b * 4 + cls * 2] = 0xFFFFFFFFu; sel[b * 4 + cls * 2 + 1] = 0xFFFFFFFFu; }
      __syncthreads();
      continue;
    }
    const uint32_t* list = cand + ((size_t)cls * B_ + b) * T_;

    for (int i2 = tid; i2 < 2048; i2 += 192) hist[i2] = 0u;
    __syncthreads();
    for (int gi = tid; gi < T_; gi += 192) {
      const int seg = gi / SEG_, off = gi - seg * SEG_;
      if ((uint32_t)off < scnt2[cls][seg]) atomicAdd(&hist[list[gi] >> 12], 1u);
    }
    __syncthreads();
    find_kth128(hist, 2048, K - 1u, tid, wsum, res);
    const uint32_t b1 = res[0], cb1 = res[1];

    for (int i2 = tid; i2 < 4096; i2 += 192) hist[i2] = 0u;
    __syncthreads();
    for (int gi = tid; gi < T_; gi += 192) {
      const int seg = gi / SEG_, off = gi - seg * SEG_;
      if ((uint32_t)off < scnt2[cls][seg]) {
        const uint32_t m = list[gi];
        if ((m >> 12) == b1) atomicAdd(&hist[m & 0xFFFu], 1u);
      }
    }
    __syncthreads();
    find_kth128(hist, 4096, K - 1u - cb1, tid, wsum, res);
    const uint32_t b2 = res[0], cb2 = res[1];
    const uint32_t Mstar = (b1 << 12) | b2;
    const uint32_t need2 = K - cb1 - cb2;
    const uint32_t cnteq = hist[b2];
    __syncthreads();

    uint32_t tstar = 0xFFFFFFFFu;
    if (need2 < cnteq) {  // mantissa tie straddles boundary: break on anchor index
      const int8_t want = (cls == 0) ? (int8_t)1 : (int8_t)0;
      const uint32_t k0 = (cls == 0) ? KF0 : KB0;
      const uint32_t k1 = (cls == 0) ? KF1 : KB1;
      const int8_t* lrow = labels + (size_t)b * T_;
      if (tid == 0) lcnt = 0u;
      __syncthreads();
      for (int s = tid; s < T_; s += 192) {
        if (lrow[s] == want) {
          const int aa2 = s / HW_, cc = s % HW_;
          const uint32_t t = (uint32_t)(cc * A_ + aa2);
          if (mant23(k0, k1, (uint32_t)b * (uint32_t)T_ + t) == Mstar) {
            const uint32_t p = atomicAdd(&lcnt, 1u);
            if (p < 4096u) hist[p] = t;
          }
        }
      }
      __syncthreads();
      if (tid == 0) {
        const uint32_t nn = lcnt < 4096u ? lcnt : 4096u;
        uint32_t prev = 0u;
        for (uint32_t kk2 = 0; kk2 < need2; ++kk2) {
          uint32_t mn2 = 0xFFFFFFFFu;
          for (uint32_t i3 = 0; i3 < nn; ++i3) {
            const uint32_t vv = hist[i3];
            if ((kk2 == 0u || vv > prev) && vv < mn2) mn2 = vv;
          }
          prev = mn2;
        }
        tstar = prev;
      }
    }
    if (tid == 0) { sel[b * 4 + cls * 2] = Mstar; sel[b * 4 + cls * 2 + 1] = tstar; }
    __syncthreads();
  }
}

// ---------------- K4: finalize + write all outputs (float4) ---------------
__global__ __launch_bounds__(192) void k4_final(const float* __restrict__ gt,
                                                const float* __restrict__ im,
                                                const int8_t* __restrict__ labels,
                                                const uint32_t* __restrict__ barg,
                                                const uint32_t* __restrict__ cnt,
                                                const uint32_t* __restrict__ sel,
                                                float* __restrict__ out) {
#pragma clang fp contract(off)
  const int b = blockIdx.y;
  const int tid = threadIdx.x;
  const int iq = blockIdx.x * 192 + tid;
  __shared__ float sgt[NGT_ * 5];
  if (tid < NGT_ * 5) sgt[tid] = gt[b * NGT_ * 5 + tid];
  __syncthreads();

  const int aa = iq / 1600;
  const int cell0 = (iq % 1600) * 4;
  const float imh = im[0], imw = im[1];
  const size_t base = (size_t)b * T_ + (size_t)aa * HW_ + cell0;
  const uint32_t lv = *(const uint32_t*)(labels + base);
  const uint32_t av = barg[base >> 2];
  const uint32_t Ms1 = sel[b * 4 + 0], ts1 = sel[b * 4 + 1];
  const uint32_t Ms0 = sel[b * 4 + 2], ts0 = sel[b * 4 + 3];
  const uint32_t cf = cnt[b * 2 + 0], cbn = cnt[b * 2 + 1];
  const uint32_t fgk = cf < NUMFG_ ? cf : NUMFG_;
  const uint32_t nbg = RPNBATCH_ - fgk;
  const uint32_t bgk = cbn < nbg ? cbn : nbg;
  const float uw = 1.0f / (float)(fgk + bgk);
  const float bx1 = c_anc[aa][0], by1 = c_anc[aa][1];
  const float bx2 = c_anc[aa][2], by2 = c_anc[aa][3];

  float labf[4], inwf[4], owwf[4], tg[4][4];
#pragma unroll
  for (int c = 0; c < 4; ++c) {
    const int cell = cell0 + c;
    const int wx = cell % W_, hy = cell / W_;
    const float ax1 = bx1 + wx * 16.0f, ay1 = by1 + hy * 16.0f;
    const float ax2 = bx2 + wx * 16.0f, ay2 = by2 + hy * 16.0f;
    const bool inside = (ax1 >= 0.0f) && (ay1 >= 0.0f) && (ax2 < imw) && (ay2 < imh);
    int lab = (int)(int8_t)(uint8_t)(lv >> (8 * c));
    const uint32_t t = (uint32_t)(cell * A_ + aa);
    const uint32_t j = (uint32_t)(b * T_) + t;
    if (lab == 1) {
      const uint32_t m = mant23(KF0, KF1, j);
      if (!(m < Ms1 || (m == Ms1 && t <= ts1))) lab = -1;
    } else if (lab == 0) {
      const uint32_t m = mant23(KB0, KB1, j);
      if (!(m < Ms0 || (m == Ms0 && t <= ts0))) lab = -1;
    }
    float t0 = 0.f, t1 = 0.f, t2 = 0.f, t3 = 0.f;
    if (inside) {
      const int bg = (int)((av >> (8 * c)) & 0xFFu);
      const float gx1 = sgt[bg * 5], gy1 = sgt[bg * 5 + 1];
      const float gx2 = sgt[bg * 5 + 2], gy2 = sgt[bg * 5 + 3];
      const float ew = ax2 - ax1 + 1.0f, eh = ay2 - ay1 + 1.0f;
      const float ecx = ax1 + 0.5f * ew, ecy = ay1 + 0.5f * eh;
      const float gw = gx2 - gx1 + 1.0f, gh = gy2 - gy1 + 1.0f;
      const float gcx = gx1 + 0.5f * gw, gcy = gy1 + 0.5f * gh;
      t0 = (gcx - ecx) / ew;
      t1 = (gcy - ecy) / eh;
      t2 = logf(gw / ew);
      t3 = logf(gh / eh);
    }
    tg[0][c] = t0; tg[1][c] = t1; tg[2][c] = t2; tg[3][c] = t3;
    labf[c] = (float)lab;
    inwf[c] = (lab == 1) ? 1.0f : 0.0f;
    owwf[c] = (lab == 1 || lab == 0) ? uw : 0.0f;
  }

  *(float4*)(out + base) = make_float4(labf[0], labf[1], labf[2], labf[3]);
  const size_t ch = ((size_t)b * 36 + (size_t)aa * 4) * HW_ + cell0;
  float* o1 = out + OUT0_;
  float* o2 = o1 + OUTC_;
  float* o3 = o2 + OUTC_;
#pragma unroll
  for (int k = 0; k < 4; ++k)
    *(float4*)(o1 + ch + (size_t)k * HW_) = make_float4(tg[k][0], tg[k][1], tg[k][2], tg[k][3]);
  const float4 iv = make_float4(inwf[0], inwf[1], inwf[2], inwf[3]);
  const float4 ovv = make_float4(owwf[0], owwf[1], owwf[2], owwf[3]);
#pragma unroll
  for (int k = 0; k < 4; ++k) {
    *(float4*)(o2 + ch + (size_t)k * HW_) = iv;
    *(float4*)(o3 + ch + (size_t)k * HW_) = ovv;
  }
}

extern "C" void kernel_launch(void* const* d_in, const int* in_sizes, int n_in,
                              void* d_out, int out_size, void* d_ws, size_t ws_size,
                              hipStream_t stream) {
  (void)in_sizes; (void)n_in; (void)out_size; (void)ws_size;
  const float* gt = (const float*)d_in[1];   // (32,20,5)
  const float* im = (const float*)d_in[2];   // (32,3)
  float* out = (float*)d_out;

  uint8_t* ws = (uint8_t*)d_ws;
  uint32_t* gpart  = (uint32_t*)(ws + 0);          // 32*20*75 u32    (192000 B)
  uint32_t* cnt    = (uint32_t*)(ws + 192000);     // 32*2 u32        (256 B)
  uint32_t* sel    = (uint32_t*)(ws + 192256);     // 32*4 u32        (512 B)
  uint32_t* dcnt   = (uint32_t*)(ws + 192768);     // 32 u32          (128 B)
  uint32_t* cntblk = (uint32_t*)(ws + 192896);     // 2*32*75 u32     (19200 B)
  int8_t*   labels = (int8_t*)  (ws + 212096);     // 32*57600 i8     (1.84 MB)
  uint32_t* barg   = (uint32_t*)(ws + 2055296);    // 32*57600 u8     (1.84 MB)
  uint32_t* bkey   = (uint32_t*)(ws + 3898496);    // 32*57600 u32    (7.37 MB)
  uint32_t* cand   = (uint32_t*)(ws + 11271296);   // 2*32*57600 u32  (14.7 MB)

  k1_iou<<<dim3(NB2_, B_), dim3(192), 0, stream>>>(gt, im, gpart, bkey, barg, dcnt);
  k2_label<<<dim3(NB2_, B_), dim3(192), 0, stream>>>(gt, im, gpart, bkey, labels,
                                                     cntblk, cand, dcnt, cnt, sel);
  k4_final<<<dim3(NB2_, B_), dim3(192), 0, stream>>>(gt, im, labels, barg, cnt, sel, out);
}

// Round 6
// 220.842 us; speedup vs baseline: 2.4344x; 2.4344x over previous
//
#include <hip/hip_runtime.h>
#include <stdint.h>
#include <stddef.h>

// JAX >= 0.5 defaults jax_threefry_partitionable=True (verified R1: absmax 0.0).
#define JAX_PARTITIONABLE 1

static constexpr int B_   = 32;
static constexpr int NGT_ = 20;
static constexpr int H_   = 64;
static constexpr int W_   = 100;
static constexpr int A_   = 9;
static constexpr int HW_  = H_ * W_;        // 6400
static constexpr int T_   = HW_ * A_;       // 57600
static constexpr int NB2_ = 75;             // blocks per image (192 thr x 4 cells)
static constexpr int SEG_ = 768;            // candidate segment per block (192*4)
static constexpr uint32_t NUMFG_ = 128u;
static constexpr uint32_t RPNBATCH_ = 256u;
static constexpr int OUT0_ = B_ * T_;
static constexpr int OUTC_ = B_ * 4 * A_ * HW_;

// ---------------- Threefry-2x32-20 (bit-exact vs JAX) ----------------
struct TF2 { uint32_t a, b; };

__host__ __device__ constexpr uint32_t rotl32(uint32_t v, int r) {
  return (v << r) | (v >> (32 - r));
}

__host__ __device__ constexpr TF2 tf2x32(uint32_t k0, uint32_t k1,
                                         uint32_t x0, uint32_t x1) {
  uint32_t ks2 = k0 ^ k1 ^ 0x1BD11BDAu;
  x0 += k0; x1 += k1;
#define TFR_(r) x0 += x1; x1 = rotl32(x1, (r)); x1 ^= x0;
  TFR_(13) TFR_(15) TFR_(26) TFR_(6)
  x0 += k1;  x1 += ks2 + 1u;
  TFR_(17) TFR_(29) TFR_(16) TFR_(24)
  x0 += ks2; x1 += k0 + 2u;
  TFR_(13) TFR_(15) TFR_(26) TFR_(6)
  x0 += k0;  x1 += k1 + 3u;
  TFR_(17) TFR_(29) TFR_(16) TFR_(24)
  x0 += k1;  x1 += ks2 + 4u;
  TFR_(13) TFR_(15) TFR_(26) TFR_(6)
  x0 += ks2; x1 += k0 + 5u;
#undef TFR_
  return TF2{x0, x1};
}

#if JAX_PARTITIONABLE
static constexpr TF2 KFk = tf2x32(0u, 42u, 0u, 0u);
static constexpr TF2 KBk = tf2x32(0u, 42u, 0u, 1u);
static constexpr uint32_t KF0 = KFk.a, KF1 = KFk.b;
static constexpr uint32_t KB0 = KBk.a, KB1 = KBk.b;
#else
static constexpr TF2 R02 = tf2x32(0u, 42u, 0u, 2u);
static constexpr TF2 R13 = tf2x32(0u, 42u, 1u, 3u);
static constexpr uint32_t KF0 = R02.a, KF1 = R13.a;
static constexpr uint32_t KB0 = R02.b, KB1 = R13.b;
#endif

__device__ inline uint32_t mant23(uint32_t k0, uint32_t k1, uint32_t j) {
#if JAX_PARTITIONABLE
  TF2 r = tf2x32(k0, k1, 0u, j);
  return (r.a ^ r.b) >> 9;
#else
  constexpr uint32_t HALF_ = (uint32_t)((uint64_t)B_ * T_ / 2);
  uint32_t lo = (j < HALF_) ? j : j - HALF_;
  TF2 r = tf2x32(k0, k1, lo, lo + HALF_);
  return ((j < HALF_) ? r.a : r.b) >> 9;
#endif
}

// monotone float->uint key; fkey(+0) = 0x80000000; strictly monotone, equality-preserving
__device__ inline uint32_t fkey(float f) {
  uint32_t u = __float_as_uint(f);
  return (u & 0x80000000u) ? ~u : (u | 0x80000000u);
}

__constant__ float c_anc[9][4] = {
  { -84.f,  -40.f,  99.f,  55.f},
  {-176.f,  -88.f, 191.f, 103.f},
  {-360.f, -184.f, 375.f, 199.f},
  { -56.f,  -56.f,  71.f,  71.f},
  {-120.f, -120.f, 135.f, 135.f},
  {-248.f, -248.f, 263.f, 263.f},
  { -36.f,  -80.f,  51.f,  95.f},
  { -80.f, -168.f,  95.f, 183.f},
  {-168.f, -344.f, 183.f, 359.f},
};

// ---------------- K1: the ONE full IOU pass --------------------------------
// 4 consecutive cells/thread. Outputs per-anchor bestkey + argmax byte, and
// per-(b,g) block-partial maxima (plain stores; k2 reduces -> no memset).
__global__ __launch_bounds__(192) void k1_iou(const float* __restrict__ gt,
                                              const float* __restrict__ im,
                                              uint32_t* __restrict__ gpart,
                                              uint32_t* __restrict__ bkey,
                                              uint32_t* __restrict__ barg) {
#pragma clang fp contract(off)
  const int b = blockIdx.y;
  const int bx = blockIdx.x;
  const int tid = threadIdx.x;
  const int iq = bx * 192 + tid;             // [0, 14400)
  __shared__ float4 sbox[NGT_];
  __shared__ float sgar[NGT_];
  __shared__ uint32_t skey[NGT_];
  __shared__ uint32_t smask;

  bool valid = false;
  if (tid < NGT_) {
    const float x1 = gt[(b * NGT_ + tid) * 5 + 0];
    const float y1 = gt[(b * NGT_ + tid) * 5 + 1];
    const float x2 = gt[(b * NGT_ + tid) * 5 + 2];
    const float y2 = gt[(b * NGT_ + tid) * 5 + 3];
    const float gw = x2 - x1 + 1.0f, gh = y2 - y1 + 1.0f;
    valid = !(gw == 1.0f && gh == 1.0f);
    sbox[tid] = make_float4(x1, y1, x2, y2);
    sgar[tid] = gw * gh;
    skey[tid] = 0u;
  }
  unsigned long long mv = __ballot(valid);   // wave 0 holds lanes 0..19
  if (tid == 0) smask = (uint32_t)mv;
  __syncthreads();

  const int aa = iq / 1600;                  // wave-uniform (1600 % 64 == 0)
  const int cell0 = (iq % 1600) * 4;
  const float imh = im[0], imw = im[1];
  const float bx1 = c_anc[aa][0], by1 = c_anc[aa][1];
  const float bx2 = c_anc[aa][2], by2 = c_anc[aa][3];

  float ax1[4], ay1[4], ax2[4], ay2[4], aarea[4];
  bool ins[4];
#pragma unroll
  for (int c = 0; c < 4; ++c) {
    const int cell = cell0 + c;
    const int wx = cell % W_, hy = cell / W_;
    ax1[c] = bx1 + wx * 16.0f;
    ay1[c] = by1 + hy * 16.0f;
    ax2[c] = bx2 + wx * 16.0f;
    ay2[c] = by2 + hy * 16.0f;
    ins[c] = (ax1[c] >= 0.0f) && (ay1[c] >= 0.0f) && (ax2[c] < imw) && (ay2[c] < imh);
    aarea[c] = (ax2[c] - ax1[c] + 1.0f) * (ay2[c] - ay1[c] + 1.0f);
  }

  uint32_t bk[4] = {0u, 0u, 0u, 0u};
  uint32_t ba[4] = {0u, 0u, 0u, 0u};
  const uint32_t mask = smask;
  const bool anyin = __ballot(ins[0] || ins[1] || ins[2] || ins[3]) != 0ull;

  if (anyin) {
    for (int g = 0; g < NGT_; ++g) {
      if (!((mask >> g) & 1u)) continue;
      const float4 gb = sbox[g];             // one ds_read_b128, broadcast
      const float gar = sgar[g];
      uint32_t gm = 0u;
#pragma unroll
      for (int c = 0; c < 4; ++c) {
        float iw = fminf(ax2[c], gb.z) - fmaxf(ax1[c], gb.x) + 1.0f;
        float ih = fminf(ay2[c], gb.w) - fmaxf(ay1[c], gb.y) + 1.0f;
        float inter = fmaxf(iw, 0.0f) * fmaxf(ih, 0.0f);
        float ua = aarea[c] + gar - inter;
        float ov = inter / ua;               // IEEE div, bit-exact vs numpy
        uint32_t k = ins[c] ? fkey(ov) : 0u;
        if (k > bk[c]) { bk[c] = k; ba[c] = (uint32_t)g; }  // first-max
        gm = k > gm ? k : gm;
      }
      for (int d = 1; d < 64; d <<= 1) {
        uint32_t o = (uint32_t)__shfl_xor((int)gm, d, 64);
        gm = (o > gm) ? o : gm;
      }
      if ((tid & 63) == 0) atomicMax(&skey[g], gm);
    }
  }
  __syncthreads();
  if (tid < NGT_) gpart[(b * NGT_ + tid) * NB2_ + bx] = skey[tid];  // plain store

  const size_t base = (size_t)b * T_ + (size_t)aa * HW_ + cell0;    // 16B aligned
  *(uint4*)(bkey + base) = make_uint4(bk[0], bk[1], bk[2], bk[3]);
  barg[base >> 2] = ba[0] | (ba[1] << 8) | (ba[2] << 16) | (ba[3] << 24);
}

// ---------------- K2: labels + per-block compaction ------------------------
__global__ __launch_bounds__(192) void k2_label(const float* __restrict__ gt,
                                                const float* __restrict__ im,
                                                const uint32_t* __restrict__ gpart,
                                                const uint32_t* __restrict__ bkey,
                                                int8_t* __restrict__ labels,
                                                uint32_t* __restrict__ cntblk,
                                                uint32_t* __restrict__ cand) {
#pragma clang fp contract(off)
  const int b = blockIdx.y;
  const int bx = blockIdx.x;
  const int tid = threadIdx.x;
  const int iq = bx * 192 + tid;
  __shared__ float4 sbox[NGT_];
  __shared__ float sgar[NGT_];
  __shared__ uint32_t skey[NGT_];
  __shared__ uint32_t smask, sminG;
  __shared__ uint32_t swc[3];

  bool valid = false;
  if (tid < NGT_) {
    const float x1 = gt[(b * NGT_ + tid) * 5 + 0];
    const float y1 = gt[(b * NGT_ + tid) * 5 + 1];
    const float x2 = gt[(b * NGT_ + tid) * 5 + 2];
    const float y2 = gt[(b * NGT_ + tid) * 5 + 3];
    const float gw = x2 - x1 + 1.0f, gh = y2 - y1 + 1.0f;
    valid = !(gw == 1.0f && gh == 1.0f);
    sbox[tid] = make_float4(x1, y1, x2, y2);
    sgar[tid] = gw * gh;
    skey[tid] = 0u;
  }
  unsigned long long mv = __ballot(valid);
  if (tid == 0) smask = (uint32_t)mv;
  __syncthreads();
  // reduce gmax from k1's 75 per-block partials (LDS atomics only)
  for (int idx = tid; idx < NGT_ * NB2_; idx += 192)
    atomicMax(&skey[idx / NB2_], gpart[b * NGT_ * NB2_ + idx]);
  __syncthreads();
  if (tid < 64) {
    uint32_t kk = 0xFFFFFFFFu;
    if (tid < NGT_ && ((smask >> tid) & 1u)) {
      uint32_t g = skey[tid];
      if (g > 0x80000000u) kk = g;   // exclude fkey(0) sentinel
    }
    for (int d = 1; d < 64; d <<= 1) {
      uint32_t o = (uint32_t)__shfl_xor((int)kk, d, 64);
      kk = (o < kk) ? o : kk;
    }
    if (tid == 0) sminG = kk;
  }
  __syncthreads();

  const int aa = iq / 1600;
  const int cell0 = (iq % 1600) * 4;
  const float imh = im[0], imw = im[1];
  const float bx1 = c_anc[aa][0], by1 = c_anc[aa][1];
  const float bx2 = c_anc[aa][2], by2 = c_anc[aa][3];
  const size_t base = (size_t)b * T_ + (size_t)aa * HW_ + cell0;
  const uint4 bk4 = *(const uint4*)(bkey + base);

  float ax1[4], ay1[4], ax2[4], ay2[4], aarea[4];
  bool ins[4], need[4];
  uint32_t bkv[4] = {bk4.x, bk4.y, bk4.z, bk4.w};
  int lab[4];
#pragma unroll
  for (int c = 0; c < 4; ++c) {
    const int cell = cell0 + c;
    const int wx = cell % W_, hy = cell / W_;
    ax1[c] = bx1 + wx * 16.0f;
    ay1[c] = by1 + hy * 16.0f;
    ax2[c] = bx2 + wx * 16.0f;
    ay2[c] = by2 + hy * 16.0f;
    ins[c] = (ax1[c] >= 0.0f) && (ay1[c] >= 0.0f) && (ax2[c] < imw) && (ay2[c] < imh);
    aarea[c] = (ax2[c] - ax1[c] + 1.0f) * (ay2[c] - ay1[c] + 1.0f);
    const float mo = __uint_as_float(bkv[c] & 0x7FFFFFFFu);
    lab[c] = -1;
    if (ins[c] && mo < 0.3f) lab[c] = 0;
    need[c] = ins[c] && bkv[c] >= sminG && mo < 0.7f;  // haskeep only possible here
    if (ins[c] && mo >= 0.7f) lab[c] = 1;
  }
  if (__ballot(need[0] || need[1] || need[2] || need[3]) != 0ull) {
    const uint32_t mask = smask;
    for (int g = 0; g < NGT_; ++g) {
      if (!((mask >> g) & 1u)) continue;
      const uint32_t gk = skey[g];
      if (gk <= 0x80000000u) continue;       // gt_max==0 -> 1e-5, never matches
      const float4 gb = sbox[g];
      const float gar = sgar[g];
#pragma unroll
      for (int c = 0; c < 4; ++c) {
        if (!need[c]) continue;
        float iw = fminf(ax2[c], gb.z) - fmaxf(ax1[c], gb.x) + 1.0f;
        float ih = fminf(ay2[c], gb.w) - fmaxf(ay1[c], gb.y) + 1.0f;
        float inter = fmaxf(iw, 0.0f) * fmaxf(ih, 0.0f);
        float ua = aarea[c] + gar - inter;
        float ov = inter / ua;
        if (fkey(ov) == gk) lab[c] = 1;
      }
    }
  }

  uint32_t lpack = 0, mant[4];
  int nf = 0, nb = 0;
#pragma unroll
  for (int c = 0; c < 4; ++c) {
    lpack |= ((uint32_t)(uint8_t)(int8_t)lab[c]) << (8 * c);
    mant[c] = 0u;
    if (lab[c] >= 0) {
      const int t = (cell0 + c) * A_ + aa;   // original anchor index (threefry j)
      mant[c] = mant23(lab[c] ? KF0 : KB0, lab[c] ? KF1 : KB1, (uint32_t)(b * T_ + t));
      if (lab[c] == 1) ++nf; else ++nb;
    }
  }
  *(uint32_t*)(labels + base) = lpack;

  // block-local compaction via packed wave prefix (nf|nb<<16), zero global atomics
  const int lane = tid & 63, wv = tid >> 6;
  uint32_t cpk = (uint32_t)nf | ((uint32_t)nb << 16);
  uint32_t incl = cpk;
  for (int d = 1; d < 64; d <<= 1) {
    uint32_t u = (uint32_t)__shfl_up((int)incl, d, 64);
    if (lane >= d) incl += u;
  }
  uint32_t wtot = (uint32_t)__shfl((int)incl, 63, 64);
  if (lane == 0) swc[wv] = wtot;
  __syncthreads();
  uint32_t woffF = 0, woffB = 0, totF = 0, totB = 0;
  for (int w = 0; w < 3; ++w) {
    uint32_t v = swc[w];
    if (w < wv) { woffF += v & 0xFFFFu; woffB += v >> 16; }
    totF += v & 0xFFFFu; totB += v >> 16;
  }
  uint32_t excl = incl - cpk;
  uint32_t posF = woffF + (excl & 0xFFFFu);
  uint32_t posB = woffB + (excl >> 16);
  uint32_t* dstF = cand + ((size_t)0 * B_ + b) * T_ + (size_t)bx * SEG_;
  uint32_t* dstB = cand + ((size_t)1 * B_ + b) * T_ + (size_t)bx * SEG_;
#pragma unroll
  for (int c = 0; c < 4; ++c) {
    if (lab[c] == 1) dstF[posF++] = mant[c];
    else if (lab[c] == 0) dstB[posB++] = mant[c];
  }
  if (tid == 0) {
    cntblk[(0 * B_ + b) * NB2_ + bx] = totF;
    cntblk[(1 * B_ + b) * NB2_ + bx] = totB;
  }
}

// ---------------- K3: K-th smallest over segmented candidates (1024 thr) ---
__device__ inline void find_kth1024(uint32_t* hist, int n, uint32_t target, int tid,
                                    uint32_t* wsum, uint32_t* res) {
  const int C = n >> 10;
  const int base = tid * C;
  uint32_t s = 0;
  for (int i = 0; i < C; ++i) s += hist[base + i];
  uint32_t v = s;
  for (int d = 1; d < 64; d <<= 1) {
    uint32_t u = (uint32_t)__shfl_up((int)v, d, 64);
    if ((tid & 63) >= d) v += u;
  }
  const int wv = tid >> 6;
  if ((tid & 63) == 63) wsum[wv] = v;
  __syncthreads();
  uint32_t woff = 0;
  for (int w2 = 0; w2 < wv; ++w2) woff += wsum[w2];
  uint32_t c = woff + v - s;
  for (int i = 0; i < C; ++i) {
    uint32_t h = hist[base + i];
    if (h != 0u && target >= c && target < c + h) {
      res[0] = (uint32_t)(base + i);
      res[1] = c;
    }
    c += h;
  }
  __syncthreads();
}

__global__ __launch_bounds__(1024) void k3_select(const int8_t* __restrict__ labels,
                                                  const uint32_t* __restrict__ cntblk,
                                                  const uint32_t* __restrict__ cand,
                                                  uint32_t* __restrict__ cnt,
                                                  uint32_t* __restrict__ sel) {
  const int b = blockIdx.x >> 1;
  const int cls = blockIdx.x & 1;  // 0=fg, 1=bg
  const int tid = threadIdx.x;
  __shared__ uint32_t scnt[NB2_];
  __shared__ uint32_t hist[4096];
  __shared__ uint32_t wsum[16];
  __shared__ uint32_t res[2];
  __shared__ uint32_t lcnt, sTot, sCf;

  if (tid == 0) { sTot = 0u; sCf = 0u; }
  __syncthreads();
  if (tid < NB2_) {
    uint32_t c = cntblk[(cls * B_ + b) * NB2_ + tid];
    scnt[tid] = c;
    atomicAdd(&sTot, c);
    if (cls == 1) atomicAdd(&sCf, cntblk[(0 * B_ + b) * NB2_ + tid]);
  }
  __syncthreads();
  const uint32_t n = sTot;
  const uint32_t cf = (cls == 0) ? n : sCf;
  if (tid == 0) cnt[b * 2 + cls] = n;  // k4 reads this next dispatch
  const uint32_t fgk = cf < NUMFG_ ? cf : NUMFG_;
  const uint32_t K = (cls == 0) ? NUMFG_ : RPNBATCH_ - fgk;
  if (n <= K) {
    if (tid == 0) { sel[b * 4 + cls * 2] = 0xFFFFFFFFu; sel[b * 4 + cls * 2 + 1] = 0xFFFFFFFFu; }
    return;
  }
  const uint32_t* list = cand + ((size_t)cls * B_ + b) * T_;

  for (int i = tid; i < 2048; i += 1024) hist[i] = 0u;
  __syncthreads();
  for (int gi = tid; gi < T_; gi += 1024) {
    const int seg = gi / SEG_, off = gi - seg * SEG_;
    if ((uint32_t)off < scnt[seg]) atomicAdd(&hist[list[gi] >> 12], 1u);
  }
  __syncthreads();
  find_kth1024(hist, 2048, K - 1u, tid, wsum, res);
  const uint32_t b1 = res[0], cb1 = res[1];
  __syncthreads();

  for (int i = tid; i < 4096; i += 1024) hist[i] = 0u;
  __syncthreads();
  for (int gi = tid; gi < T_; gi += 1024) {
    const int seg = gi / SEG_, off = gi - seg * SEG_;
    if ((uint32_t)off < scnt[seg]) {
      const uint32_t m = list[gi];
      if ((m >> 12) == b1) atomicAdd(&hist[m & 0xFFFu], 1u);
    }
  }
  __syncthreads();
  find_kth1024(hist, 4096, K - 1u - cb1, tid, wsum, res);
  const uint32_t b2 = res[0], cb2 = res[1];
  const uint32_t Mstar = (b1 << 12) | b2;
  const uint32_t need = K - cb1 - cb2;
  const uint32_t cnteq = hist[b2];
  __syncthreads();

  uint32_t tstar = 0xFFFFFFFFu;
  if (need < cnteq) {  // mantissa tie straddles boundary: break on anchor index
    const int8_t want = (cls == 0) ? (int8_t)1 : (int8_t)0;
    const uint32_t k0 = (cls == 0) ? KF0 : KB0;
    const uint32_t k1 = (cls == 0) ? KF1 : KB1;
    const int8_t* lrow = labels + (size_t)b * T_;
    if (tid == 0) lcnt = 0u;
    __syncthreads();
    for (int s = tid; s < T_; s += 1024) {
      if (lrow[s] == want) {
        const int aa = s / HW_, cc = s % HW_;
        const uint32_t t = (uint32_t)(cc * A_ + aa);
        if (mant23(k0, k1, (uint32_t)b * (uint32_t)T_ + t) == Mstar) {
          const uint32_t p = atomicAdd(&lcnt, 1u);
          if (p < 4096u) hist[p] = t;
        }
      }
    }
    __syncthreads();
    if (tid == 0) {
      const uint32_t nn = lcnt < 4096u ? lcnt : 4096u;
      uint32_t prev = 0u;
      for (uint32_t kk = 0; kk < need; ++kk) {
        uint32_t mn2 = 0xFFFFFFFFu;
        for (uint32_t i2 = 0; i2 < nn; ++i2) {
          const uint32_t vv = hist[i2];
          if ((kk == 0u || vv > prev) && vv < mn2) mn2 = vv;
        }
        prev = mn2;
      }
      tstar = prev;
    }
  }
  if (tid == 0) { sel[b * 4 + cls * 2] = Mstar; sel[b * 4 + cls * 2 + 1] = tstar; }
}

// ---------------- K4: finalize + write all outputs (float4) ---------------
__global__ __launch_bounds__(192) void k4_final(const float* __restrict__ gt,
                                                const float* __restrict__ im,
                                                const int8_t* __restrict__ labels,
                                                const uint32_t* __restrict__ barg,
                                                const uint32_t* __restrict__ cnt,
                                                const uint32_t* __restrict__ sel,
                                                float* __restrict__ out) {
#pragma clang fp contract(off)
  const int b = blockIdx.y;
  const int tid = threadIdx.x;
  const int iq = blockIdx.x * 192 + tid;
  __shared__ float sgt[NGT_ * 5];
  if (tid < NGT_ * 5) sgt[tid] = gt[b * NGT_ * 5 + tid];
  __syncthreads();

  const int aa = iq / 1600;
  const int cell0 = (iq % 1600) * 4;
  const float imh = im[0], imw = im[1];
  const size_t base = (size_t)b * T_ + (size_t)aa * HW_ + cell0;
  const uint32_t lv = *(const uint32_t*)(labels + base);
  const uint32_t av = barg[base >> 2];
  const uint32_t Ms1 = sel[b * 4 + 0], ts1 = sel[b * 4 + 1];
  const uint32_t Ms0 = sel[b * 4 + 2], ts0 = sel[b * 4 + 3];
  const uint32_t cf = cnt[b * 2 + 0], cbn = cnt[b * 2 + 1];
  const uint32_t fgk = cf < NUMFG_ ? cf : NUMFG_;
  const uint32_t nbg = RPNBATCH_ - fgk;
  const uint32_t bgk = cbn < nbg ? cbn : nbg;
  const float uw = 1.0f / (float)(fgk + bgk);
  const float bx1 = c_anc[aa][0], by1 = c_anc[aa][1];
  const float bx2 = c_anc[aa][2], by2 = c_anc[aa][3];

  float labf[4], inwf[4], owwf[4], tg[4][4];
#pragma unroll
  for (int c = 0; c < 4; ++c) {
    const int cell = cell0 + c;
    const int wx = cell % W_, hy = cell / W_;
    const float ax1 = bx1 + wx * 16.0f, ay1 = by1 + hy * 16.0f;
    const float ax2 = bx2 + wx * 16.0f, ay2 = by2 + hy * 16.0f;
    const bool inside = (ax1 >= 0.0f) && (ay1 >= 0.0f) && (ax2 < imw) && (ay2 < imh);
    int lab = (int)(int8_t)(uint8_t)(lv >> (8 * c));
    const uint32_t t = (uint32_t)(cell * A_ + aa);
    const uint32_t j = (uint32_t)(b * T_) + t;
    if (lab == 1) {
      const uint32_t m = mant23(KF0, KF1, j);
      if (!(m < Ms1 || (m == Ms1 && t <= ts1))) lab = -1;
    } else if (lab == 0) {
      const uint32_t m = mant23(KB0, KB1, j);
      if (!(m < Ms0 || (m == Ms0 && t <= ts0))) lab = -1;
    }
    float t0 = 0.f, t1 = 0.f, t2 = 0.f, t3 = 0.f;
    if (inside) {
      const int bg = (int)((av >> (8 * c)) & 0xFFu);
      const float gx1 = sgt[bg * 5], gy1 = sgt[bg * 5 + 1];
      const float gx2 = sgt[bg * 5 + 2], gy2 = sgt[bg * 5 + 3];
      const float ew = ax2 - ax1 + 1.0f, eh = ay2 - ay1 + 1.0f;
      const float ecx = ax1 + 0.5f * ew, ecy = ay1 + 0.5f * eh;
      const float gw = gx2 - gx1 + 1.0f, gh = gy2 - gy1 + 1.0f;
      const float gcx = gx1 + 0.5f * gw, gcy = gy1 + 0.5f * gh;
      t0 = (gcx - ecx) / ew;
      t1 = (gcy - ecy) / eh;
      t2 = logf(gw / ew);
      t3 = logf(gh / eh);
    }
    tg[0][c] = t0; tg[1][c] = t1; tg[2][c] = t2; tg[3][c] = t3;
    labf[c] = (float)lab;
    inwf[c] = (lab == 1) ? 1.0f : 0.0f;
    owwf[c] = (lab == 1 || lab == 0) ? uw : 0.0f;
  }

  *(float4*)(out + base) = make_float4(labf[0], labf[1], labf[2], labf[3]);
  const size_t ch = ((size_t)b * 36 + (size_t)aa * 4) * HW_ + cell0;
  float* o1 = out + OUT0_;
  float* o2 = o1 + OUTC_;
  float* o3 = o2 + OUTC_;
#pragma unroll
  for (int k = 0; k < 4; ++k)
    *(float4*)(o1 + ch + (size_t)k * HW_) = make_float4(tg[k][0], tg[k][1], tg[k][2], tg[k][3]);
  const float4 iv = make_float4(inwf[0], inwf[1], inwf[2], inwf[3]);
  const float4 ovv = make_float4(owwf[0], owwf[1], owwf[2], owwf[3]);
#pragma unroll
  for (int k = 0; k < 4; ++k) {
    *(float4*)(o2 + ch + (size_t)k * HW_) = iv;
    *(float4*)(o3 + ch + (size_t)k * HW_) = ovv;
  }
}

extern "C" void kernel_launch(void* const* d_in, const int* in_sizes, int n_in,
                              void* d_out, int out_size, void* d_ws, size_t ws_size,
                              hipStream_t stream) {
  (void)in_sizes; (void)n_in; (void)out_size; (void)ws_size;
  const float* gt = (const float*)d_in[1];   // (32,20,5)
  const float* im = (const float*)d_in[2];   // (32,3)
  float* out = (float*)d_out;

  uint8_t* ws = (uint8_t*)d_ws;
  uint32_t* gpart  = (uint32_t*)(ws + 0);          // 32*20*75 u32    (192000 B)
  uint32_t* cnt    = (uint32_t*)(ws + 192000);     // 32*2 u32        (256 B)
  uint32_t* sel    = (uint32_t*)(ws + 192256);     // 32*4 u32        (512 B)
  uint32_t* cntblk = (uint32_t*)(ws + 192768);     // 2*32*75 u32     (19200 B)
  int8_t*   labels = (int8_t*)  (ws + 211968);     // 32*57600 i8     (1.84 MB)
  uint32_t* barg   = (uint32_t*)(ws + 2055168);    // 32*57600 u8     (1.84 MB)
  uint32_t* bkey   = (uint32_t*)(ws + 3898368);    // 32*57600 u32    (7.37 MB)
  uint32_t* cand   = (uint32_t*)(ws + 11271168);   // 2*32*57600 u32  (14.7 MB)

  k1_iou<<<dim3(NB2_, B_), dim3(192), 0, stream>>>(gt, im, gpart, bkey, barg);
  k2_label<<<dim3(NB2_, B_), dim3(192), 0, stream>>>(gt, im, gpart, bkey, labels,
                                                     cntblk, cand);
  k3_select<<<dim3(B_ * 2), dim3(1024), 0, stream>>>(labels, cntblk, cand, cnt, sel);
  k4_final<<<dim3(NB2_, B_), dim3(192), 0, stream>>>(gt, im, labels, barg, cnt, sel, out);
}

// Round 7
// 184.666 us; speedup vs baseline: 2.9113x; 1.1959x over previous
//
#include <hip/hip_runtime.h>
#include <stdint.h>
#include <stddef.h>

// JAX >= 0.5 defaults jax_threefry_partitionable=True (verified R1: absmax 0.0).
#define JAX_PARTITIONABLE 1

static constexpr int B_   = 32;
static constexpr int NGT_ = 20;
static constexpr int H_   = 64;
static constexpr int W_   = 100;
static constexpr int A_   = 9;
static constexpr int HW_  = H_ * W_;        // 6400
static constexpr int T_   = HW_ * A_;       // 57600
static constexpr int NB2_ = 75;             // blocks per image (192 thr x 4 cells)
static constexpr int SEG_ = 768;            // candidate segment per block (192*4)
static constexpr uint32_t NUMFG_ = 128u;
static constexpr uint32_t RPNBATCH_ = 256u;
static constexpr int OUT0_ = B_ * T_;
static constexpr int OUTC_ = B_ * 4 * A_ * HW_;

// ---------------- Threefry-2x32-20 (bit-exact vs JAX) ----------------
struct TF2 { uint32_t a, b; };

__host__ __device__ constexpr uint32_t rotl32(uint32_t v, int r) {
  return (v << r) | (v >> (32 - r));
}

__host__ __device__ constexpr TF2 tf2x32(uint32_t k0, uint32_t k1,
                                         uint32_t x0, uint32_t x1) {
  uint32_t ks2 = k0 ^ k1 ^ 0x1BD11BDAu;
  x0 += k0; x1 += k1;
#define TFR_(r) x0 += x1; x1 = rotl32(x1, (r)); x1 ^= x0;
  TFR_(13) TFR_(15) TFR_(26) TFR_(6)
  x0 += k1;  x1 += ks2 + 1u;
  TFR_(17) TFR_(29) TFR_(16) TFR_(24)
  x0 += ks2; x1 += k0 + 2u;
  TFR_(13) TFR_(15) TFR_(26) TFR_(6)
  x0 += k0;  x1 += k1 + 3u;
  TFR_(17) TFR_(29) TFR_(16) TFR_(24)
  x0 += k1;  x1 += ks2 + 4u;
  TFR_(13) TFR_(15) TFR_(26) TFR_(6)
  x0 += ks2; x1 += k0 + 5u;
#undef TFR_
  return TF2{x0, x1};
}

#if JAX_PARTITIONABLE
static constexpr TF2 KFk = tf2x32(0u, 42u, 0u, 0u);
static constexpr TF2 KBk = tf2x32(0u, 42u, 0u, 1u);
static constexpr uint32_t KF0 = KFk.a, KF1 = KFk.b;
static constexpr uint32_t KB0 = KBk.a, KB1 = KBk.b;
#else
static constexpr TF2 R02 = tf2x32(0u, 42u, 0u, 2u);
static constexpr TF2 R13 = tf2x32(0u, 42u, 1u, 3u);
static constexpr uint32_t KF0 = R02.a, KF1 = R13.a;
static constexpr uint32_t KB0 = R02.b, KB1 = R13.b;
#endif

__device__ inline uint32_t mant23(uint32_t k0, uint32_t k1, uint32_t j) {
#if JAX_PARTITIONABLE
  TF2 r = tf2x32(k0, k1, 0u, j);
  return (r.a ^ r.b) >> 9;
#else
  constexpr uint32_t HALF_ = (uint32_t)((uint64_t)B_ * T_ / 2);
  uint32_t lo = (j < HALF_) ? j : j - HALF_;
  TF2 r = tf2x32(k0, k1, lo, lo + HALF_);
  return ((j < HALF_) ? r.a : r.b) >> 9;
#endif
}

// monotone float->uint key; fkey(+0) = 0x80000000; strictly monotone, equality-preserving
__device__ inline uint32_t fkey(float f) {
  uint32_t u = __float_as_uint(f);
  return (u & 0x80000000u) ? ~u : (u | 0x80000000u);
}

__constant__ float c_anc[9][4] = {
  { -84.f,  -40.f,  99.f,  55.f},
  {-176.f,  -88.f, 191.f, 103.f},
  {-360.f, -184.f, 375.f, 199.f},
  { -56.f,  -56.f,  71.f,  71.f},
  {-120.f, -120.f, 135.f, 135.f},
  {-248.f, -248.f, 263.f, 263.f},
  { -36.f,  -80.f,  51.f,  95.f},
  { -80.f, -168.f,  95.f, 183.f},
  {-168.f, -344.f, 183.f, 359.f},
};

// ---------------- K12: single IOU pass + labels + compaction ---------------
// gmax[b][g] computed ANALYTICALLY per block: for fixed anchor shape a,
// iw(wx) and ih(hy) are separable concave piecewise-linear; the float grid
// max is at the plateau clamped to the inside-feasible integer range
// (float eval is monotone in iw/ih; <=4 integer candidates per axis bracket
// the real optimum). Value is evaluated with the canonical float expression
// so equality vs the per-anchor loop is bitwise.
__global__ __launch_bounds__(192) void k12(const float* __restrict__ gt,
                                           const float* __restrict__ im,
                                           int8_t* __restrict__ labels,
                                           uint32_t* __restrict__ barg,
                                           uint32_t* __restrict__ cntblk,
                                           uint32_t* __restrict__ cand) {
#pragma clang fp contract(off)
  const int b = blockIdx.y;
  const int bx = blockIdx.x;
  const int tid = threadIdx.x;
  const int iq = bx * 192 + tid;
  __shared__ float4 sbox[NGT_];
  __shared__ float sgar[NGT_];
  __shared__ uint32_t skey[NGT_];
  __shared__ uint32_t smask;
  __shared__ uint32_t swc[3];

  bool valid = false;
  if (tid < NGT_) {
    const float x1 = gt[(b * NGT_ + tid) * 5 + 0];
    const float y1 = gt[(b * NGT_ + tid) * 5 + 1];
    const float x2 = gt[(b * NGT_ + tid) * 5 + 2];
    const float y2 = gt[(b * NGT_ + tid) * 5 + 3];
    const float gw = x2 - x1 + 1.0f, gh = y2 - y1 + 1.0f;
    valid = !(gw == 1.0f && gh == 1.0f);
    sbox[tid] = make_float4(x1, y1, x2, y2);
    sgar[tid] = gw * gh;
    skey[tid] = 0u;
  }
  unsigned long long mv = __ballot(valid);   // wave 0 holds lanes 0..19
  if (tid == 0) smask = (uint32_t)mv;
  __syncthreads();

  const float imh = im[0], imw = im[1];

  // ---- analytic per-(shape, gt) gmax: 180 one-thread evals ----
  if (tid < A_ * NGT_) {
    const int g = tid % NGT_, a = tid / NGT_;
    if ((smask >> g) & 1u) {
      const float a0 = c_anc[a][0], a1v = c_anc[a][1];
      const float a2 = c_anc[a][2], a3v = c_anc[a][3];
      const int wxL = max(0, (int)ceilf(-a0 / 16.0f));
      const int wxH = min(W_ - 1, (int)floorf((imw - 1.0f - a2) / 16.0f));
      const int hyL = max(0, (int)ceilf(-a1v / 16.0f));
      const int hyH = min(H_ - 1, (int)floorf((imh - 1.0f - a3v) / 16.0f));
      if (wxL <= wxH && hyL <= hyH) {
        const float4 gb = sbox[g];
        // best wx (maximize raw iw; concave => candidates bracket plateau)
        float pu = (gb.z - a2) / 16.0f, pv = (gb.x - a0) / 16.0f;
        float p1 = fminf(pu, pv), p2 = fmaxf(pu, pv);
        const int f1x = (int)floorf(p1), f2x = (int)floorf(p2);
        int cx[4] = {f1x, f1x + 1, f2x, f2x + 1};
        float bw = -1e30f; int bxx = wxL;
        for (int i = 0; i < 4; ++i) {
          int x = cx[i] < wxL ? wxL : (cx[i] > wxH ? wxH : cx[i]);
          float iw = fminf(a2 + x * 16.0f, gb.z) - fmaxf(a0 + x * 16.0f, gb.x) + 1.0f;
          if (iw > bw) { bw = iw; bxx = x; }
        }
        // best hy
        pu = (gb.w - a3v) / 16.0f; pv = (gb.y - a1v) / 16.0f;
        p1 = fminf(pu, pv); p2 = fmaxf(pu, pv);
        const int f1y = (int)floorf(p1), f2y = (int)floorf(p2);
        int cy[4] = {f1y, f1y + 1, f2y, f2y + 1};
        float bh = -1e30f; int byy = hyL;
        for (int i = 0; i < 4; ++i) {
          int y = cy[i] < hyL ? hyL : (cy[i] > hyH ? hyH : cy[i]);
          float ih = fminf(a3v + y * 16.0f, gb.w) - fmaxf(a1v + y * 16.0f, gb.y) + 1.0f;
          if (ih > bh) { bh = ih; byy = y; }
        }
        // canonical eval at (bxx, byy) -- identical float path as main loop
        const float ax1 = a0 + bxx * 16.0f, ay1 = a1v + byy * 16.0f;
        const float ax2 = a2 + bxx * 16.0f, ay2 = a3v + byy * 16.0f;
        const float aarea = (ax2 - ax1 + 1.0f) * (ay2 - ay1 + 1.0f);
        float iw = fminf(ax2, gb.z) - fmaxf(ax1, gb.x) + 1.0f;
        float ih = fminf(ay2, gb.w) - fmaxf(ay1, gb.y) + 1.0f;
        float inter = fmaxf(iw, 0.0f) * fmaxf(ih, 0.0f);
        float ua = aarea + sgar[g] - inter;
        float ov = inter / ua;
        atomicMax(&skey[g], fkey(ov));
      }
    }
  }
  __syncthreads();

  // ---- the one per-anchor IOU loop: bestkey + argmax + haskeep inline ----
  const int aa = iq / 1600;                  // wave-uniform (1600 % 64 == 0)
  const int cell0 = (iq % 1600) * 4;
  const float bx1 = c_anc[aa][0], by1 = c_anc[aa][1];
  const float bx2 = c_anc[aa][2], by2 = c_anc[aa][3];

  float ax1[4], ay1[4], ax2[4], ay2[4], aarea[4];
  bool ins[4];
#pragma unroll
  for (int c = 0; c < 4; ++c) {
    const int cell = cell0 + c;
    const int wx = cell % W_, hy = cell / W_;
    ax1[c] = bx1 + wx * 16.0f;
    ay1[c] = by1 + hy * 16.0f;
    ax2[c] = bx2 + wx * 16.0f;
    ay2[c] = by2 + hy * 16.0f;
    ins[c] = (ax1[c] >= 0.0f) && (ay1[c] >= 0.0f) && (ax2[c] < imw) && (ay2[c] < imh);
    aarea[c] = (ax2[c] - ax1[c] + 1.0f) * (ay2[c] - ay1[c] + 1.0f);
  }

  uint32_t bk[4] = {0u, 0u, 0u, 0u};
  uint32_t ba[4] = {0u, 0u, 0u, 0u};
  bool hk[4] = {false, false, false, false};
  const uint32_t mask = smask;
  const bool anyin = __ballot(ins[0] || ins[1] || ins[2] || ins[3]) != 0ull;

  if (anyin) {
    for (int g = 0; g < NGT_; ++g) {
      if (!((mask >> g) & 1u)) continue;
      const float4 gb = sbox[g];             // ds_read_b128, broadcast
      const float gar = sgar[g];
      const uint32_t gk = skey[g];
#pragma unroll
      for (int c = 0; c < 4; ++c) {
        float iw = fminf(ax2[c], gb.z) - fmaxf(ax1[c], gb.x) + 1.0f;
        float ih = fminf(ay2[c], gb.w) - fmaxf(ay1[c], gb.y) + 1.0f;
        float inter = fmaxf(iw, 0.0f) * fmaxf(ih, 0.0f);
        float ua = aarea[c] + gar - inter;
        float ov = inter / ua;               // IEEE div, bit-exact vs numpy
        uint32_t k = ins[c] ? fkey(ov) : 0u;
        if (k > bk[c]) { bk[c] = k; ba[c] = (uint32_t)g; }  // first-max
        if (k == gk && gk > 0x80000000u) hk[c] = true;      // keep (gt_max==0 sentinel excluded)
      }
    }
  }

  int lab[4];
  uint32_t lpack = 0, mant[4];
  int nf = 0, nb = 0;
#pragma unroll
  for (int c = 0; c < 4; ++c) {
    lab[c] = -1;
    if (ins[c]) {
      const float mo = __uint_as_float(bk[c] & 0x7FFFFFFFu);  // inside => ov>=0
      if (mo < 0.3f) lab[c] = 0;
      if (hk[c]) lab[c] = 1;
      if (mo >= 0.7f) lab[c] = 1;
    }
    lpack |= ((uint32_t)(uint8_t)(int8_t)lab[c]) << (8 * c);
    mant[c] = 0u;
    if (lab[c] >= 0) {
      const int t = (cell0 + c) * A_ + aa;   // original anchor index (threefry j)
      mant[c] = mant23(lab[c] ? KF0 : KB0, lab[c] ? KF1 : KB1, (uint32_t)(b * T_ + t));
      if (lab[c] == 1) ++nf; else ++nb;
    }
  }
  const size_t base = (size_t)b * T_ + (size_t)aa * HW_ + cell0;  // 4B aligned
  *(uint32_t*)(labels + base) = lpack;
  barg[base >> 2] = ba[0] | (ba[1] << 8) | (ba[2] << 16) | (ba[3] << 24);

  // block-local compaction via packed wave prefix (nf|nb<<16), zero global atomics
  const int lane = tid & 63, wv = tid >> 6;
  uint32_t cpk = (uint32_t)nf | ((uint32_t)nb << 16);
  uint32_t incl = cpk;
  for (int d = 1; d < 64; d <<= 1) {
    uint32_t u = (uint32_t)__shfl_up((int)incl, d, 64);
    if (lane >= d) incl += u;
  }
  uint32_t wtot = (uint32_t)__shfl((int)incl, 63, 64);
  if (lane == 0) swc[wv] = wtot;
  __syncthreads();
  uint32_t woffF = 0, woffB = 0, totF = 0, totB = 0;
  for (int w = 0; w < 3; ++w) {
    uint32_t v = swc[w];
    if (w < wv) { woffF += v & 0xFFFFu; woffB += v >> 16; }
    totF += v & 0xFFFFu; totB += v >> 16;
  }
  uint32_t excl = incl - cpk;
  uint32_t posF = woffF + (excl & 0xFFFFu);
  uint32_t posB = woffB + (excl >> 16);
  uint32_t* dstF = cand + ((size_t)0 * B_ + b) * T_ + (size_t)bx * SEG_;
  uint32_t* dstB = cand + ((size_t)1 * B_ + b) * T_ + (size_t)bx * SEG_;
#pragma unroll
  for (int c = 0; c < 4; ++c) {
    if (lab[c] == 1) dstF[posF++] = mant[c];
    else if (lab[c] == 0) dstB[posB++] = mant[c];
  }
  if (tid == 0) {
    cntblk[(0 * B_ + b) * NB2_ + bx] = totF;
    cntblk[(1 * B_ + b) * NB2_ + bx] = totB;
  }
}

// ---------------- K3: K-th smallest over segmented candidates (1024 thr) ---
__device__ inline void find_kth1024(uint32_t* hist, int n, uint32_t target, int tid,
                                    uint32_t* wsum, uint32_t* res) {
  const int C = n >> 10;
  const int base = tid * C;
  uint32_t s = 0;
  for (int i = 0; i < C; ++i) s += hist[base + i];
  uint32_t v = s;
  for (int d = 1; d < 64; d <<= 1) {
    uint32_t u = (uint32_t)__shfl_up((int)v, d, 64);
    if ((tid & 63) >= d) v += u;
  }
  const int wv = tid >> 6;
  if ((tid & 63) == 63) wsum[wv] = v;
  __syncthreads();
  uint32_t woff = 0;
  for (int w2 = 0; w2 < wv; ++w2) woff += wsum[w2];
  uint32_t c = woff + v - s;
  for (int i = 0; i < C; ++i) {
    uint32_t h = hist[base + i];
    if (h != 0u && target >= c && target < c + h) {
      res[0] = (uint32_t)(base + i);
      res[1] = c;
    }
    c += h;
  }
  __syncthreads();
}

__global__ __launch_bounds__(1024) void k3_select(const int8_t* __restrict__ labels,
                                                  const uint32_t* __restrict__ cntblk,
                                                  const uint32_t* __restrict__ cand,
                                                  uint32_t* __restrict__ cnt,
                                                  uint32_t* __restrict__ sel) {
  const int b = blockIdx.x >> 1;
  const int cls = blockIdx.x & 1;  // 0=fg, 1=bg
  const int tid = threadIdx.x;
  __shared__ uint32_t scnt[NB2_];
  __shared__ uint32_t hist[4096];
  __shared__ uint32_t wsum[16];
  __shared__ uint32_t res[2];
  __shared__ uint32_t lcnt, sTot, sCf;

  if (tid == 0) { sTot = 0u; sCf = 0u; }
  __syncthreads();
  if (tid < NB2_) {
    uint32_t c = cntblk[(cls * B_ + b) * NB2_ + tid];
    scnt[tid] = c;
    atomicAdd(&sTot, c);
    if (cls == 1) atomicAdd(&sCf, cntblk[(0 * B_ + b) * NB2_ + tid]);
  }
  __syncthreads();
  const uint32_t n = sTot;
  const uint32_t cf = (cls == 0) ? n : sCf;
  if (tid == 0) cnt[b * 2 + cls] = n;  // k4 reads this next dispatch
  const uint32_t fgk = cf < NUMFG_ ? cf : NUMFG_;
  const uint32_t K = (cls == 0) ? NUMFG_ : RPNBATCH_ - fgk;
  if (n <= K) {
    if (tid == 0) { sel[b * 4 + cls * 2] = 0xFFFFFFFFu; sel[b * 4 + cls * 2 + 1] = 0xFFFFFFFFu; }
    return;
  }
  const uint32_t* list = cand + ((size_t)cls * B_ + b) * T_;

  for (int i = tid; i < 2048; i += 1024) hist[i] = 0u;
  __syncthreads();
  for (int gi = tid; gi < T_; gi += 1024) {
    const int seg = gi / SEG_, off = gi - seg * SEG_;
    if ((uint32_t)off < scnt[seg]) atomicAdd(&hist[list[gi] >> 12], 1u);
  }
  __syncthreads();
  find_kth1024(hist, 2048, K - 1u, tid, wsum, res);
  const uint32_t b1 = res[0], cb1 = res[1];
  __syncthreads();

  for (int i = tid; i < 4096; i += 1024) hist[i] = 0u;
  __syncthreads();
  for (int gi = tid; gi < T_; gi += 1024) {
    const int seg = gi / SEG_, off = gi - seg * SEG_;
    if ((uint32_t)off < scnt[seg]) {
      const uint32_t m = list[gi];
      if ((m >> 12) == b1) atomicAdd(&hist[m & 0xFFFu], 1u);
    }
  }
  __syncthreads();
  find_kth1024(hist, 4096, K - 1u - cb1, tid, wsum, res);
  const uint32_t b2 = res[0], cb2 = res[1];
  const uint32_t Mstar = (b1 << 12) | b2;
  const uint32_t need = K - cb1 - cb2;
  const uint32_t cnteq = hist[b2];
  __syncthreads();

  uint32_t tstar = 0xFFFFFFFFu;
  if (need < cnteq) {  // mantissa tie straddles boundary: break on anchor index
    const int8_t want = (cls == 0) ? (int8_t)1 : (int8_t)0;
    const uint32_t k0 = (cls == 0) ? KF0 : KB0;
    const uint32_t k1 = (cls == 0) ? KF1 : KB1;
    const int8_t* lrow = labels + (size_t)b * T_;
    if (tid == 0) lcnt = 0u;
    __syncthreads();
    for (int s = tid; s < T_; s += 1024) {
      if (lrow[s] == want) {
        const int aa = s / HW_, cc = s % HW_;
        const uint32_t t = (uint32_t)(cc * A_ + aa);
        if (mant23(k0, k1, (uint32_t)b * (uint32_t)T_ + t) == Mstar) {
          const uint32_t p = atomicAdd(&lcnt, 1u);
          if (p < 4096u) hist[p] = t;
        }
      }
    }
    __syncthreads();
    if (tid == 0) {
      const uint32_t nn = lcnt < 4096u ? lcnt : 4096u;
      uint32_t prev = 0u;
      for (uint32_t kk = 0; kk < need; ++kk) {
        uint32_t mn2 = 0xFFFFFFFFu;
        for (uint32_t i2 = 0; i2 < nn; ++i2) {
          const uint32_t vv = hist[i2];
          if ((kk == 0u || vv > prev) && vv < mn2) mn2 = vv;
        }
        prev = mn2;
      }
      tstar = prev;
    }
  }
  if (tid == 0) { sel[b * 4 + cls * 2] = Mstar; sel[b * 4 + cls * 2 + 1] = tstar; }
}

// ---------------- K4: finalize + write all outputs (float4) ---------------
__global__ __launch_bounds__(192) void k4_final(const float* __restrict__ gt,
                                                const float* __restrict__ im,
                                                const int8_t* __restrict__ labels,
                                                const uint32_t* __restrict__ barg,
                                                const uint32_t* __restrict__ cnt,
                                                const uint32_t* __restrict__ sel,
                                                float* __restrict__ out) {
#pragma clang fp contract(off)
  const int b = blockIdx.y;
  const int tid = threadIdx.x;
  const int iq = blockIdx.x * 192 + tid;
  __shared__ float sgt[NGT_ * 5];
  if (tid < NGT_ * 5) sgt[tid] = gt[b * NGT_ * 5 + tid];
  __syncthreads();

  const int aa = iq / 1600;
  const int cell0 = (iq % 1600) * 4;
  const float imh = im[0], imw = im[1];
  const size_t base = (size_t)b * T_ + (size_t)aa * HW_ + cell0;
  const uint32_t lv = *(const uint32_t*)(labels + base);
  const uint32_t av = barg[base >> 2];
  const uint32_t Ms1 = sel[b * 4 + 0], ts1 = sel[b * 4 + 1];
  const uint32_t Ms0 = sel[b * 4 + 2], ts0 = sel[b * 4 + 3];
  const uint32_t cf = cnt[b * 2 + 0], cbn = cnt[b * 2 + 1];
  const uint32_t fgk = cf < NUMFG_ ? cf : NUMFG_;
  const uint32_t nbg = RPNBATCH_ - fgk;
  const uint32_t bgk = cbn < nbg ? cbn : nbg;
  const float uw = 1.0f / (float)(fgk + bgk);
  const float bx1 = c_anc[aa][0], by1 = c_anc[aa][1];
  const float bx2 = c_anc[aa][2], by2 = c_anc[aa][3];

  float labf[4], inwf[4], owwf[4], tg[4][4];
#pragma unroll
  for (int c = 0; c < 4; ++c) {
    const int cell = cell0 + c;
    const int wx = cell % W_, hy = cell / W_;
    const float ax1 = bx1 + wx * 16.0f, ay1 = by1 + hy * 16.0f;
    const float ax2 = bx2 + wx * 16.0f, ay2 = by2 + hy * 16.0f;
    const bool inside = (ax1 >= 0.0f) && (ay1 >= 0.0f) && (ax2 < imw) && (ay2 < imh);
    int lab = (int)(int8_t)(uint8_t)(lv >> (8 * c));
    const uint32_t t = (uint32_t)(cell * A_ + aa);
    const uint32_t j = (uint32_t)(b * T_) + t;
    if (lab == 1) {
      const uint32_t m = mant23(KF0, KF1, j);
      if (!(m < Ms1 || (m == Ms1 && t <= ts1))) lab = -1;
    } else if (lab == 0) {
      const uint32_t m = mant23(KB0, KB1, j);
      if (!(m < Ms0 || (m == Ms0 && t <= ts0))) lab = -1;
    }
    float t0 = 0.f, t1 = 0.f, t2 = 0.f, t3 = 0.f;
    if (inside) {
      const int bg = (int)((av >> (8 * c)) & 0xFFu);
      const float gx1 = sgt[bg * 5], gy1 = sgt[bg * 5 + 1];
      const float gx2 = sgt[bg * 5 + 2], gy2 = sgt[bg * 5 + 3];
      const float ew = ax2 - ax1 + 1.0f, eh = ay2 - ay1 + 1.0f;
      const float ecx = ax1 + 0.5f * ew, ecy = ay1 + 0.5f * eh;
      const float gw = gx2 - gx1 + 1.0f, gh = gy2 - gy1 + 1.0f;
      const float gcx = gx1 + 0.5f * gw, gcy = gy1 + 0.5f * gh;
      t0 = (gcx - ecx) / ew;
      t1 = (gcy - ecy) / eh;
      t2 = logf(gw / ew);
      t3 = logf(gh / eh);
    }
    tg[0][c] = t0; tg[1][c] = t1; tg[2][c] = t2; tg[3][c] = t3;
    labf[c] = (float)lab;
    inwf[c] = (lab == 1) ? 1.0f : 0.0f;
    owwf[c] = (lab == 1 || lab == 0) ? uw : 0.0f;
  }

  *(float4*)(out + base) = make_float4(labf[0], labf[1], labf[2], labf[3]);
  const size_t ch = ((size_t)b * 36 + (size_t)aa * 4) * HW_ + cell0;
  float* o1 = out + OUT0_;
  float* o2 = o1 + OUTC_;
  float* o3 = o2 + OUTC_;
#pragma unroll
  for (int k = 0; k < 4; ++k)
    *(float4*)(o1 + ch + (size_t)k * HW_) = make_float4(tg[k][0], tg[k][1], tg[k][2], tg[k][3]);
  const float4 iv = make_float4(inwf[0], inwf[1], inwf[2], inwf[3]);
  const float4 ovv = make_float4(owwf[0], owwf[1], owwf[2], owwf[3]);
#pragma unroll
  for (int k = 0; k < 4; ++k) {
    *(float4*)(o2 + ch + (size_t)k * HW_) = iv;
    *(float4*)(o3 + ch + (size_t)k * HW_) = ovv;
  }
}

extern "C" void kernel_launch(void* const* d_in, const int* in_sizes, int n_in,
                              void* d_out, int out_size, void* d_ws, size_t ws_size,
                              hipStream_t stream) {
  (void)in_sizes; (void)n_in; (void)out_size; (void)ws_size;
  const float* gt = (const float*)d_in[1];   // (32,20,5)
  const float* im = (const float*)d_in[2];   // (32,3)
  float* out = (float*)d_out;

  uint8_t* ws = (uint8_t*)d_ws;
  uint32_t* cnt    = (uint32_t*)(ws + 0);          // 32*2 u32        (256 B)
  uint32_t* sel    = (uint32_t*)(ws + 256);        // 32*4 u32        (512 B)
  uint32_t* cntblk = (uint32_t*)(ws + 768);        // 2*32*75 u32     (19200 B)
  int8_t*   labels = (int8_t*)  (ws + 19968);      // 32*57600 i8     (1.84 MB)
  uint32_t* barg   = (uint32_t*)(ws + 1863168);    // 32*57600 u8     (1.84 MB)
  uint32_t* cand   = (uint32_t*)(ws + 3706368);    // 2*32*57600 u32  (14.7 MB)

  k12<<<dim3(NB2_, B_), dim3(192), 0, stream>>>(gt, im, labels, barg, cntblk, cand);
  k3_select<<<dim3(B_ * 2), dim3(1024), 0, stream>>>(labels, cntblk, cand, cnt, sel);
  k4_final<<<dim3(NB2_, B_), dim3(192), 0, stream>>>(gt, im, labels, barg, cnt, sel, out);
}

// Round 8
// 168.333 us; speedup vs baseline: 3.1937x; 1.0970x over previous
//
#include <hip/hip_runtime.h>
#include <stdint.h>
#include <stddef.h>

// JAX >= 0.5 defaults jax_threefry_partitionable=True (verified R1: absmax 0.0).
#define JAX_PARTITIONABLE 1

static constexpr int B_   = 32;
static constexpr int NGT_ = 20;
static constexpr int H_   = 64;
static constexpr int W_   = 100;
static constexpr int A_   = 9;
static constexpr int HW_  = H_ * W_;        // 6400
static constexpr int T_   = HW_ * A_;       // 57600
static constexpr int NB2_ = 75;             // blocks per image (192 thr x 4 cells)
static constexpr int SEG_ = 768;            // candidate segment per block (192*4)
static constexpr uint32_t NUMFG_ = 128u;
static constexpr uint32_t RPNBATCH_ = 256u;
static constexpr int OUT0_ = B_ * T_;
static constexpr int OUTC_ = B_ * 4 * A_ * HW_;

// ---------------- Threefry-2x32-20 (bit-exact vs JAX) ----------------
struct TF2 { uint32_t a, b; };

__host__ __device__ constexpr uint32_t rotl32(uint32_t v, int r) {
  return (v << r) | (v >> (32 - r));
}

__host__ __device__ constexpr TF2 tf2x32(uint32_t k0, uint32_t k1,
                                         uint32_t x0, uint32_t x1) {
  uint32_t ks2 = k0 ^ k1 ^ 0x1BD11BDAu;
  x0 += k0; x1 += k1;
#define TFR_(r) x0 += x1; x1 = rotl32(x1, (r)); x1 ^= x0;
  TFR_(13) TFR_(15) TFR_(26) TFR_(6)
  x0 += k1;  x1 += ks2 + 1u;
  TFR_(17) TFR_(29) TFR_(16) TFR_(24)
  x0 += ks2; x1 += k0 + 2u;
  TFR_(13) TFR_(15) TFR_(26) TFR_(6)
  x0 += k0;  x1 += k1 + 3u;
  TFR_(17) TFR_(29) TFR_(16) TFR_(24)
  x0 += k1;  x1 += ks2 + 4u;
  TFR_(13) TFR_(15) TFR_(26) TFR_(6)
  x0 += ks2; x1 += k0 + 5u;
#undef TFR_
  return TF2{x0, x1};
}

#if JAX_PARTITIONABLE
static constexpr TF2 KFk = tf2x32(0u, 42u, 0u, 0u);
static constexpr TF2 KBk = tf2x32(0u, 42u, 0u, 1u);
static constexpr uint32_t KF0 = KFk.a, KF1 = KFk.b;
static constexpr uint32_t KB0 = KBk.a, KB1 = KBk.b;
#else
static constexpr TF2 R02 = tf2x32(0u, 42u, 0u, 2u);
static constexpr TF2 R13 = tf2x32(0u, 42u, 1u, 3u);
static constexpr uint32_t KF0 = R02.a, KF1 = R13.a;
static constexpr uint32_t KB0 = R02.b, KB1 = R13.b;
#endif

__device__ inline uint32_t mant23(uint32_t k0, uint32_t k1, uint32_t j) {
#if JAX_PARTITIONABLE
  TF2 r = tf2x32(k0, k1, 0u, j);
  return (r.a ^ r.b) >> 9;
#else
  constexpr uint32_t HALF_ = (uint32_t)((uint64_t)B_ * T_ / 2);
  uint32_t lo = (j < HALF_) ? j : j - HALF_;
  TF2 r = tf2x32(k0, k1, lo, lo + HALF_);
  return ((j < HALF_) ? r.a : r.b) >> 9;
#endif
}

// monotone float->uint key; fkey(+0) = 0x80000000; strictly monotone, equality-preserving
__device__ inline uint32_t fkey(float f) {
  uint32_t u = __float_as_uint(f);
  return (u & 0x80000000u) ? ~u : (u | 0x80000000u);
}

__constant__ float c_anc[9][4] = {
  { -84.f,  -40.f,  99.f,  55.f},
  {-176.f,  -88.f, 191.f, 103.f},
  {-360.f, -184.f, 375.f, 199.f},
  { -56.f,  -56.f,  71.f,  71.f},
  {-120.f, -120.f, 135.f, 135.f},
  {-248.f, -248.f, 263.f, 263.f},
  { -36.f,  -80.f,  51.f,  95.f},
  { -80.f, -168.f,  95.f, 183.f},
  {-168.f, -344.f, 183.f, 359.f},
};

// ---------------- K12: single IOU pass + labels + compaction ---------------
// gmax[b][g] computed ANALYTICALLY per block: for fixed anchor shape a,
// iw(wx) and ih(hy) are separable concave piecewise-linear; the float grid
// max is at the plateau clamped to the inside-feasible integer range
// (float eval is monotone in iw/ih; <=4 integer candidates per axis bracket
// the real optimum). Value is evaluated with the canonical float expression
// so equality vs the per-anchor loop is bitwise.
__global__ __launch_bounds__(192) void k12(const float* __restrict__ gt,
                                           const float* __restrict__ im,
                                           int8_t* __restrict__ labels,
                                           uint32_t* __restrict__ barg,
                                           uint32_t* __restrict__ cntblk,
                                           uint32_t* __restrict__ cand) {
#pragma clang fp contract(off)
  const int b = blockIdx.y;
  const int bx = blockIdx.x;
  const int tid = threadIdx.x;
  const int iq = bx * 192 + tid;
  __shared__ float4 sbox[NGT_];
  __shared__ float sgar[NGT_];
  __shared__ uint32_t skey[NGT_];
  __shared__ uint32_t smask;
  __shared__ uint32_t swc[3];

  bool valid = false;
  if (tid < NGT_) {
    const float x1 = gt[(b * NGT_ + tid) * 5 + 0];
    const float y1 = gt[(b * NGT_ + tid) * 5 + 1];
    const float x2 = gt[(b * NGT_ + tid) * 5 + 2];
    const float y2 = gt[(b * NGT_ + tid) * 5 + 3];
    const float gw = x2 - x1 + 1.0f, gh = y2 - y1 + 1.0f;
    valid = !(gw == 1.0f && gh == 1.0f);
    sbox[tid] = make_float4(x1, y1, x2, y2);
    sgar[tid] = gw * gh;
    skey[tid] = 0u;
  }
  unsigned long long mv = __ballot(valid);   // wave 0 holds lanes 0..19
  if (tid == 0) smask = (uint32_t)mv;
  __syncthreads();

  const float imh = im[0], imw = im[1];

  // ---- analytic per-(shape, gt) gmax: 180 one-thread evals ----
  if (tid < A_ * NGT_) {
    const int g = tid % NGT_, a = tid / NGT_;
    if ((smask >> g) & 1u) {
      const float a0 = c_anc[a][0], a1v = c_anc[a][1];
      const float a2 = c_anc[a][2], a3v = c_anc[a][3];
      const int wxL = max(0, (int)ceilf(-a0 / 16.0f));
      const int wxH = min(W_ - 1, (int)floorf((imw - 1.0f - a2) / 16.0f));
      const int hyL = max(0, (int)ceilf(-a1v / 16.0f));
      const int hyH = min(H_ - 1, (int)floorf((imh - 1.0f - a3v) / 16.0f));
      if (wxL <= wxH && hyL <= hyH) {
        const float4 gb = sbox[g];
        // best wx (maximize raw iw; concave => candidates bracket plateau)
        float pu = (gb.z - a2) / 16.0f, pv = (gb.x - a0) / 16.0f;
        float p1 = fminf(pu, pv), p2 = fmaxf(pu, pv);
        const int f1x = (int)floorf(p1), f2x = (int)floorf(p2);
        int cx[4] = {f1x, f1x + 1, f2x, f2x + 1};
        float bw = -1e30f; int bxx = wxL;
        for (int i = 0; i < 4; ++i) {
          int x = cx[i] < wxL ? wxL : (cx[i] > wxH ? wxH : cx[i]);
          float iw = fminf(a2 + x * 16.0f, gb.z) - fmaxf(a0 + x * 16.0f, gb.x) + 1.0f;
          if (iw > bw) { bw = iw; bxx = x; }
        }
        // best hy
        pu = (gb.w - a3v) / 16.0f; pv = (gb.y - a1v) / 16.0f;
        p1 = fminf(pu, pv); p2 = fmaxf(pu, pv);
        const int f1y = (int)floorf(p1), f2y = (int)floorf(p2);
        int cy[4] = {f1y, f1y + 1, f2y, f2y + 1};
        float bh = -1e30f; int byy = hyL;
        for (int i = 0; i < 4; ++i) {
          int y = cy[i] < hyL ? hyL : (cy[i] > hyH ? hyH : cy[i]);
          float ih = fminf(a3v + y * 16.0f, gb.w) - fmaxf(a1v + y * 16.0f, gb.y) + 1.0f;
          if (ih > bh) { bh = ih; byy = y; }
        }
        // canonical eval at (bxx, byy) -- identical float path as main loop
        const float ax1 = a0 + bxx * 16.0f, ay1 = a1v + byy * 16.0f;
        const float ax2 = a2 + bxx * 16.0f, ay2 = a3v + byy * 16.0f;
        const float aarea = (ax2 - ax1 + 1.0f) * (ay2 - ay1 + 1.0f);
        float iw = fminf(ax2, gb.z) - fmaxf(ax1, gb.x) + 1.0f;
        float ih = fminf(ay2, gb.w) - fmaxf(ay1, gb.y) + 1.0f;
        float inter = fmaxf(iw, 0.0f) * fmaxf(ih, 0.0f);
        float ua = aarea + sgar[g] - inter;
        float ov = inter / ua;
        atomicMax(&skey[g], fkey(ov));
      }
    }
  }
  __syncthreads();

  // ---- the one per-anchor IOU loop: bestkey + argmax + haskeep inline ----
  const int aa = iq / 1600;                  // wave-uniform (1600 % 64 == 0)
  const int cell0 = (iq % 1600) * 4;
  const float bx1 = c_anc[aa][0], by1 = c_anc[aa][1];
  const float bx2 = c_anc[aa][2], by2 = c_anc[aa][3];

  float ax1[4], ay1[4], ax2[4], ay2[4], aarea[4];
  bool ins[4];
#pragma unroll
  for (int c = 0; c < 4; ++c) {
    const int cell = cell0 + c;
    const int wx = cell % W_, hy = cell / W_;
    ax1[c] = bx1 + wx * 16.0f;
    ay1[c] = by1 + hy * 16.0f;
    ax2[c] = bx2 + wx * 16.0f;
    ay2[c] = by2 + hy * 16.0f;
    ins[c] = (ax1[c] >= 0.0f) && (ay1[c] >= 0.0f) && (ax2[c] < imw) && (ay2[c] < imh);
    aarea[c] = (ax2[c] - ax1[c] + 1.0f) * (ay2[c] - ay1[c] + 1.0f);
  }

  uint32_t bk[4] = {0u, 0u, 0u, 0u};
  uint32_t ba[4] = {0u, 0u, 0u, 0u};
  bool hk[4] = {false, false, false, false};
  const uint32_t mask = smask;
  const bool anyin = __ballot(ins[0] || ins[1] || ins[2] || ins[3]) != 0ull;

  if (anyin) {
    for (int g = 0; g < NGT_; ++g) {
      if (!((mask >> g) & 1u)) continue;
      const float4 gb = sbox[g];             // ds_read_b128, broadcast
      const float gar = sgar[g];
      const uint32_t gk = skey[g];
#pragma unroll
      for (int c = 0; c < 4; ++c) {
        float iw = fminf(ax2[c], gb.z) - fmaxf(ax1[c], gb.x) + 1.0f;
        float ih = fminf(ay2[c], gb.w) - fmaxf(ay1[c], gb.y) + 1.0f;
        float inter = fmaxf(iw, 0.0f) * fmaxf(ih, 0.0f);
        float ua = aarea[c] + gar - inter;
        float ov = inter / ua;               // IEEE div, bit-exact vs numpy
        uint32_t k = ins[c] ? fkey(ov) : 0u;
        if (k > bk[c]) { bk[c] = k; ba[c] = (uint32_t)g; }  // first-max
        if (k == gk && gk > 0x80000000u) hk[c] = true;      // keep (gt_max==0 sentinel excluded)
      }
    }
  }

  int lab[4];
  uint32_t lpack = 0, mant[4];
  int nf = 0, nb = 0;
#pragma unroll
  for (int c = 0; c < 4; ++c) {
    lab[c] = -1;
    if (ins[c]) {
      const float mo = __uint_as_float(bk[c] & 0x7FFFFFFFu);  // inside => ov>=0
      if (mo < 0.3f) lab[c] = 0;
      if (hk[c]) lab[c] = 1;
      if (mo >= 0.7f) lab[c] = 1;
    }
    lpack |= ((uint32_t)(uint8_t)(int8_t)lab[c]) << (8 * c);
    mant[c] = 0u;
    if (lab[c] >= 0) {
      const int t = (cell0 + c) * A_ + aa;   // original anchor index (threefry j)
      mant[c] = mant23(lab[c] ? KF0 : KB0, lab[c] ? KF1 : KB1, (uint32_t)(b * T_ + t));
      if (lab[c] == 1) ++nf; else ++nb;
    }
  }
  const size_t base = (size_t)b * T_ + (size_t)aa * HW_ + cell0;  // 4B aligned
  *(uint32_t*)(labels + base) = lpack;
  barg[base >> 2] = ba[0] | (ba[1] << 8) | (ba[2] << 16) | (ba[3] << 24);

  // block-local compaction via packed wave prefix (nf|nb<<16), zero global atomics
  const int lane = tid & 63, wv = tid >> 6;
  uint32_t cpk = (uint32_t)nf | ((uint32_t)nb << 16);
  uint32_t incl = cpk;
  for (int d = 1; d < 64; d <<= 1) {
    uint32_t u = (uint32_t)__shfl_up((int)incl, d, 64);
    if (lane >= d) incl += u;
  }
  uint32_t wtot = (uint32_t)__shfl((int)incl, 63, 64);
  if (lane == 0) swc[wv] = wtot;
  __syncthreads();
  uint32_t woffF = 0, woffB = 0, totF = 0, totB = 0;
  for (int w = 0; w < 3; ++w) {
    uint32_t v = swc[w];
    if (w < wv) { woffF += v & 0xFFFFu; woffB += v >> 16; }
    totF += v & 0xFFFFu; totB += v >> 16;
  }
  uint32_t excl = incl - cpk;
  uint32_t posF = woffF + (excl & 0xFFFFu);
  uint32_t posB = woffB + (excl >> 16);
  uint32_t* dstF = cand + ((size_t)0 * B_ + b) * T_ + (size_t)bx * SEG_;
  uint32_t* dstB = cand + ((size_t)1 * B_ + b) * T_ + (size_t)bx * SEG_;
#pragma unroll
  for (int c = 0; c < 4; ++c) {
    if (lab[c] == 1) dstF[posF++] = mant[c];
    else if (lab[c] == 0) dstB[posB++] = mant[c];
  }
  if (tid == 0) {
    cntblk[(0 * B_ + b) * NB2_ + bx] = totF;
    cntblk[(1 * B_ + b) * NB2_ + bx] = totB;
  }
}

// ---------------- K3: K-th smallest over segmented candidates (1024 thr) ---
__device__ inline void find_kth1024(uint32_t* hist, int n, uint32_t target, int tid,
                                    uint32_t* wsum, uint32_t* res) {
  const int C = n >> 10;
  const int base = tid * C;
  uint32_t s = 0;
  for (int i = 0; i < C; ++i) s += hist[base + i];
  uint32_t v = s;
  for (int d = 1; d < 64; d <<= 1) {
    uint32_t u = (uint32_t)__shfl_up((int)v, d, 64);
    if ((tid & 63) >= d) v += u;
  }
  const int wv = tid >> 6;
  if ((tid & 63) == 63) wsum[wv] = v;
  __syncthreads();
  uint32_t woff = 0;
  for (int w2 = 0; w2 < wv; ++w2) woff += wsum[w2];
  uint32_t c = woff + v - s;
  for (int i = 0; i < C; ++i) {
    uint32_t h = hist[base + i];
    if (h != 0u && target >= c && target < c + h) {
      res[0] = (uint32_t)(base + i);
      res[1] = c;
    }
    c += h;
  }
  __syncthreads();
}

__global__ __launch_bounds__(1024) void k3_select(const int8_t* __restrict__ labels,
                                                  const uint32_t* __restrict__ cntblk,
                                                  const uint32_t* __restrict__ cand,
                                                  uint32_t* __restrict__ cnt,
                                                  uint32_t* __restrict__ sel) {
  const int b = blockIdx.x >> 1;
  const int cls = blockIdx.x & 1;  // 0=fg, 1=bg
  const int tid = threadIdx.x;
  __shared__ uint32_t scnt[NB2_];
  __shared__ uint32_t hist[4096];
  __shared__ uint32_t wsum[16];
  __shared__ uint32_t res[2];
  __shared__ uint32_t lcnt, sTot, sCf;

  if (tid == 0) { sTot = 0u; sCf = 0u; }
  __syncthreads();
  if (tid < NB2_) {
    uint32_t c = cntblk[(cls * B_ + b) * NB2_ + tid];
    scnt[tid] = c;
    atomicAdd(&sTot, c);
    if (cls == 1) atomicAdd(&sCf, cntblk[(0 * B_ + b) * NB2_ + tid]);
  }
  __syncthreads();
  const uint32_t n = sTot;
  const uint32_t cf = (cls == 0) ? n : sCf;
  if (tid == 0) cnt[b * 2 + cls] = n;  // k4 reads this next dispatch
  const uint32_t fgk = cf < NUMFG_ ? cf : NUMFG_;
  const uint32_t K = (cls == 0) ? NUMFG_ : RPNBATCH_ - fgk;
  if (n <= K) {
    if (tid == 0) { sel[b * 4 + cls * 2] = 0xFFFFFFFFu; sel[b * 4 + cls * 2 + 1] = 0xFFFFFFFFu; }
    return;
  }
  const uint32_t* list = cand + ((size_t)cls * B_ + b) * T_;
  const uint4* list4 = (const uint4*)list;   // 16B-aligned (offsets all x16)

  // level 1: top 11 bits (uint4 scan: 4x fewer iterations)
  for (int i = tid; i < 2048; i += 1024) hist[i] = 0u;
  __syncthreads();
  for (int q = tid; q < T_ / 4; q += 1024) {
    const int gi0 = q * 4;
    const int seg = gi0 / SEG_;               // SEG_%4==0 -> all 4 in same segment
    const uint32_t off = (uint32_t)(gi0 - seg * SEG_);
    const uint32_t c = scnt[seg];
    if (off < c) {
      const uint4 v = list4[q];
      atomicAdd(&hist[v.x >> 12], 1u);
      if (off + 1 < c) atomicAdd(&hist[v.y >> 12], 1u);
      if (off + 2 < c) atomicAdd(&hist[v.z >> 12], 1u);
      if (off + 3 < c) atomicAdd(&hist[v.w >> 12], 1u);
    }
  }
  __syncthreads();
  find_kth1024(hist, 2048, K - 1u, tid, wsum, res);
  const uint32_t b1 = res[0], cb1 = res[1];
  __syncthreads();

  // level 2: low 12 bits within bucket b1 (uint4 scan)
  for (int i = tid; i < 4096; i += 1024) hist[i] = 0u;
  __syncthreads();
  for (int q = tid; q < T_ / 4; q += 1024) {
    const int gi0 = q * 4;
    const int seg = gi0 / SEG_;
    const uint32_t off = (uint32_t)(gi0 - seg * SEG_);
    const uint32_t c = scnt[seg];
    if (off < c) {
      const uint4 v = list4[q];
      if ((v.x >> 12) == b1) atomicAdd(&hist[v.x & 0xFFFu], 1u);
      if (off + 1 < c && (v.y >> 12) == b1) atomicAdd(&hist[v.y & 0xFFFu], 1u);
      if (off + 2 < c && (v.z >> 12) == b1) atomicAdd(&hist[v.z & 0xFFFu], 1u);
      if (off + 3 < c && (v.w >> 12) == b1) atomicAdd(&hist[v.w & 0xFFFu], 1u);
    }
  }
  __syncthreads();
  find_kth1024(hist, 4096, K - 1u - cb1, tid, wsum, res);
  const uint32_t b2 = res[0], cb2 = res[1];
  const uint32_t Mstar = (b1 << 12) | b2;
  const uint32_t need = K - cb1 - cb2;
  const uint32_t cnteq = hist[b2];
  __syncthreads();

  uint32_t tstar = 0xFFFFFFFFu;
  if (need < cnteq) {  // mantissa tie straddles boundary: break on anchor index
    const int8_t want = (cls == 0) ? (int8_t)1 : (int8_t)0;
    const uint32_t k0 = (cls == 0) ? KF0 : KB0;
    const uint32_t k1 = (cls == 0) ? KF1 : KB1;
    const int8_t* lrow = labels + (size_t)b * T_;
    if (tid == 0) lcnt = 0u;
    __syncthreads();
    for (int s = tid; s < T_; s += 1024) {
      if (lrow[s] == want) {
        const int aa = s / HW_, cc = s % HW_;
        const uint32_t t = (uint32_t)(cc * A_ + aa);
        if (mant23(k0, k1, (uint32_t)b * (uint32_t)T_ + t) == Mstar) {
          const uint32_t p = atomicAdd(&lcnt, 1u);
          if (p < 4096u) hist[p] = t;
        }
      }
    }
    __syncthreads();
    if (tid == 0) {
      const uint32_t nn = lcnt < 4096u ? lcnt : 4096u;
      uint32_t prev = 0u;
      for (uint32_t kk = 0; kk < need; ++kk) {
        uint32_t mn2 = 0xFFFFFFFFu;
        for (uint32_t i2 = 0; i2 < nn; ++i2) {
          const uint32_t vv = hist[i2];
          if ((kk == 0u || vv > prev) && vv < mn2) mn2 = vv;
        }
        prev = mn2;
      }
      tstar = prev;
    }
  }
  if (tid == 0) { sel[b * 4 + cls * 2] = Mstar; sel[b * 4 + cls * 2 + 1] = tstar; }
}

// ---------------- K4: finalize + write all outputs (float4) ---------------
__global__ __launch_bounds__(192) void k4_final(const float* __restrict__ gt,
                                                const float* __restrict__ im,
                                                const int8_t* __restrict__ labels,
                                                const uint32_t* __restrict__ barg,
                                                const uint32_t* __restrict__ cnt,
                                                const uint32_t* __restrict__ sel,
                                                float* __restrict__ out) {
#pragma clang fp contract(off)
  const int b = blockIdx.y;
  const int tid = threadIdx.x;
  const int iq = blockIdx.x * 192 + tid;
  __shared__ float4 sbox[NGT_];   // gt boxes as float4 -> ds_read_b128 per lookup
  if (tid < NGT_) {
    sbox[tid] = make_float4(gt[(b * NGT_ + tid) * 5 + 0],
                            gt[(b * NGT_ + tid) * 5 + 1],
                            gt[(b * NGT_ + tid) * 5 + 2],
                            gt[(b * NGT_ + tid) * 5 + 3]);
  }
  __syncthreads();

  const int aa = iq / 1600;
  const int cell0 = (iq % 1600) * 4;
  const float imh = im[0], imw = im[1];
  const size_t base = (size_t)b * T_ + (size_t)aa * HW_ + cell0;
  const uint32_t lv = *(const uint32_t*)(labels + base);
  const uint32_t av = barg[base >> 2];
  const uint32_t Ms1 = sel[b * 4 + 0], ts1 = sel[b * 4 + 1];
  const uint32_t Ms0 = sel[b * 4 + 2], ts0 = sel[b * 4 + 3];
  const uint32_t cf = cnt[b * 2 + 0], cbn = cnt[b * 2 + 1];
  const uint32_t fgk = cf < NUMFG_ ? cf : NUMFG_;
  const uint32_t nbg = RPNBATCH_ - fgk;
  const uint32_t bgk = cbn < nbg ? cbn : nbg;
  const float uw = 1.0f / (float)(fgk + bgk);
  const float bx1 = c_anc[aa][0], by1 = c_anc[aa][1];
  const float bx2 = c_anc[aa][2], by2 = c_anc[aa][3];

  float labf[4], inwf[4], owwf[4], tg[4][4];
#pragma unroll
  for (int c = 0; c < 4; ++c) {
    const int cell = cell0 + c;
    const int wx = cell % W_, hy = cell / W_;
    const float ax1 = bx1 + wx * 16.0f, ay1 = by1 + hy * 16.0f;
    const float ax2 = bx2 + wx * 16.0f, ay2 = by2 + hy * 16.0f;
    const bool inside = (ax1 >= 0.0f) && (ay1 >= 0.0f) && (ax2 < imw) && (ay2 < imh);
    int lab = (int)(int8_t)(uint8_t)(lv >> (8 * c));
    const uint32_t t = (uint32_t)(cell * A_ + aa);
    const uint32_t j = (uint32_t)(b * T_) + t;
    if (lab == 1) {
      const uint32_t m = mant23(KF0, KF1, j);
      if (!(m < Ms1 || (m == Ms1 && t <= ts1))) lab = -1;
    } else if (lab == 0) {
      const uint32_t m = mant23(KB0, KB1, j);
      if (!(m < Ms0 || (m == Ms0 && t <= ts0))) lab = -1;
    }
    float t0 = 0.f, t1 = 0.f, t2 = 0.f, t3 = 0.f;
    if (inside) {
      const int bg = (int)((av >> (8 * c)) & 0xFFu);
      const float4 gb = sbox[bg];
      const float gx1 = gb.x, gy1 = gb.y, gx2 = gb.z, gy2 = gb.w;
      const float ew = ax2 - ax1 + 1.0f, eh = ay2 - ay1 + 1.0f;
      const float ecx = ax1 + 0.5f * ew, ecy = ay1 + 0.5f * eh;
      const float gw = gx2 - gx1 + 1.0f, gh = gy2 - gy1 + 1.0f;
      const float gcx = gx1 + 0.5f * gw, gcy = gy1 + 0.5f * gh;
      t0 = (gcx - ecx) / ew;
      t1 = (gcy - ecy) / eh;
      t2 = logf(gw / ew);
      t3 = logf(gh / eh);
    }
    tg[0][c] = t0; tg[1][c] = t1; tg[2][c] = t2; tg[3][c] = t3;
    labf[c] = (float)lab;
    inwf[c] = (lab == 1) ? 1.0f : 0.0f;
    owwf[c] = (lab == 1 || lab == 0) ? uw : 0.0f;
  }

  *(float4*)(out + base) = make_float4(labf[0], labf[1], labf[2], labf[3]);
  const size_t ch = ((size_t)b * 36 + (size_t)aa * 4) * HW_ + cell0;
  float* o1 = out + OUT0_;
  float* o2 = o1 + OUTC_;
  float* o3 = o2 + OUTC_;
#pragma unroll
  for (int k = 0; k < 4; ++k)
    *(float4*)(o1 + ch + (size_t)k * HW_) = make_float4(tg[k][0], tg[k][1], tg[k][2], tg[k][3]);
  const float4 iv = make_float4(inwf[0], inwf[1], inwf[2], inwf[3]);
  const float4 ovv = make_float4(owwf[0], owwf[1], owwf[2], owwf[3]);
#pragma unroll
  for (int k = 0; k < 4; ++k) {
    *(float4*)(o2 + ch + (size_t)k * HW_) = iv;
    *(float4*)(o3 + ch + (size_t)k * HW_) = ovv;
  }
}

extern "C" void kernel_launch(void* const* d_in, const int* in_sizes, int n_in,
                              void* d_out, int out_size, void* d_ws, size_t ws_size,
                              hipStream_t stream) {
  (void)in_sizes; (void)n_in; (void)out_size; (void)ws_size;
  const float* gt = (const float*)d_in[1];   // (32,20,5)
  const float* im = (const float*)d_in[2];   // (32,3)
  float* out = (float*)d_out;

  uint8_t* ws = (uint8_t*)d_ws;
  uint32_t* cnt    = (uint32_t*)(ws + 0);          // 32*2 u32        (256 B)
  uint32_t* sel    = (uint32_t*)(ws + 256);        // 32*4 u32        (512 B)
  uint32_t* cntblk = (uint32_t*)(ws + 768);        // 2*32*75 u32     (19200 B)
  int8_t*   labels = (int8_t*)  (ws + 19968);      // 32*57600 i8     (1.84 MB)
  uint32_t* barg   = (uint32_t*)(ws + 1863168);    // 32*57600 u8     (1.84 MB)
  uint32_t* cand   = (uint32_t*)(ws + 3706368);    // 2*32*57600 u32  (14.7 MB)

  k12<<<dim3(NB2_, B_), dim3(192), 0, stream>>>(gt, im, labels, barg, cntblk, cand);
  k3_select<<<dim3(B_ * 2), dim3(1024), 0, stream>>>(labels, cntblk, cand, cnt, sel);
  k4_final<<<dim3(NB2_, B_), dim3(192), 0, stream>>>(gt, im, labels, barg, cnt, sel, out);
}